// Round 1
// baseline (35059.235 us; speedup 1.0000x reference)
//
#include <hip/hip_runtime.h>
#include <stdint.h>

#define TSTEPS 512
#define BATCH  32
#define HID    512
#define G4     2048   // 4*HID gate width
#define OUTW   1024   // 2*HID output width

__device__ __forceinline__ float sigf(float x) { return 1.0f / (1.0f + __expf(-x)); }
__device__ __forceinline__ float tanhf_fast(float x) { return 2.0f / (1.0f + __expf(-2.0f * x)) - 1.0f; }

// fp32 -> bf16 round-to-nearest-even (finite inputs only)
__device__ __forceinline__ unsigned short f2bf(float f) {
    unsigned int u = __float_as_uint(f);
    u += 0x7fffu + ((u >> 16) & 1u);
    return (unsigned short)(u >> 16);
}

// xw[m, n] = sum_k X[b=(m&31), t=(m>>5), k] * W[k, n] + bias[n]
// X logical [32, 512, K] row-major; xw row m = t*32 + b; M=16384, N=2048.
// 128x128 tile, BK=16, 256 threads, 8x8 micro-tile.
template <typename XWT>
__global__ __launch_bounds__(256) void gemm_xw(
    const float* __restrict__ X, int K,
    const float* __restrict__ W,
    const float* __restrict__ bias,
    XWT* __restrict__ XW)
{
    __shared__ float As[16][132];
    __shared__ float Bs[16][132];
    const int tid = threadIdx.x;
    const int n0 = blockIdx.x * 128;
    const int m0 = blockIdx.y * 128;
    const int tx = tid & 15;
    const int ty = tid >> 4;

    // A tile loads: row mA (0..127), k-chunk kA (0 or 8)
    const int mA = tid >> 1;
    const int kA = (tid & 1) * 8;
    const int mg = m0 + mA;
    const float* arow = X + (size_t)(mg & 31) * ((size_t)TSTEPS * K) + (size_t)(mg >> 5) * K;

    // B tile loads: row kB (0..15), col chunk nB (0..120)
    const int kB = tid >> 4;
    const int nB = (tid & 15) * 8;
    const float* bptr = W + (size_t)kB * G4 + n0 + nB;

    float c[8][8];
    #pragma unroll
    for (int i = 0; i < 8; ++i)
        #pragma unroll
        for (int j = 0; j < 8; ++j) c[i][j] = 0.0f;

    for (int k0 = 0; k0 < K; k0 += 16) {
        float4 a0 = *(const float4*)(arow + k0 + kA);
        float4 a1 = *(const float4*)(arow + k0 + kA + 4);
        float4 b0 = *(const float4*)(bptr + (size_t)k0 * G4);
        float4 b1 = *(const float4*)(bptr + (size_t)k0 * G4 + 4);
        __syncthreads();
        As[kA + 0][mA] = a0.x; As[kA + 1][mA] = a0.y;
        As[kA + 2][mA] = a0.z; As[kA + 3][mA] = a0.w;
        As[kA + 4][mA] = a1.x; As[kA + 5][mA] = a1.y;
        As[kA + 6][mA] = a1.z; As[kA + 7][mA] = a1.w;
        *(float4*)&Bs[kB][nB]     = b0;
        *(float4*)&Bs[kB][nB + 4] = b1;
        __syncthreads();
        #pragma unroll
        for (int kk = 0; kk < 16; ++kk) {
            float4 av0 = *(const float4*)&As[kk][ty * 8];
            float4 av1 = *(const float4*)&As[kk][ty * 8 + 4];
            float4 bv0 = *(const float4*)&Bs[kk][tx * 8];
            float4 bv1 = *(const float4*)&Bs[kk][tx * 8 + 4];
            float a[8]  = {av0.x, av0.y, av0.z, av0.w, av1.x, av1.y, av1.z, av1.w};
            float bb[8] = {bv0.x, bv0.y, bv0.z, bv0.w, bv1.x, bv1.y, bv1.z, bv1.w};
            #pragma unroll
            for (int i = 0; i < 8; ++i)
                #pragma unroll
                for (int j = 0; j < 8; ++j)
                    c[i][j] = fmaf(a[i], bb[j], c[i][j]);
        }
    }

    float bn[8];
    #pragma unroll
    for (int j = 0; j < 8; ++j) bn[j] = bias[n0 + tx * 8 + j];

    #pragma unroll
    for (int i = 0; i < 8; ++i) {
        const int m = m0 + ty * 8 + i;
        XWT* orow = XW + (size_t)m * G4 + n0 + tx * 8;
        #pragma unroll
        for (int j = 0; j < 8; ++j) {
            float v = c[i][j] + bn[j];
            if constexpr (sizeof(XWT) == 4) { orow[j] = (XWT)v; }
            else                            { orow[j] = (XWT)f2bf(v); }
        }
    }
}

// One block per (batch, dir). 512 threads; thread tid owns z columns
// 4*tid..4*tid+3 for the matvec, and h-column tid for the gate update.
// h lives in LDS (broadcast operand), c in a register.
template <typename XWT>
__global__ __launch_bounds__(512) void lstm_scan(
    const XWT* __restrict__ xw_f,   // [T, B, 2048]
    const XWT* __restrict__ xw_b,
    const float* __restrict__ Wh_f, // [512, 2048]
    const float* __restrict__ Wh_b,
    float* __restrict__ out)        // [B, T, 1024]
{
    __shared__ float h_lds[HID];
    __shared__ float z_lds[G4];

    const int tid = threadIdx.x;          // 0..511
    const int dir = blockIdx.x & 1;       // even/odd -> one Wh per XCD L2
    const int b   = blockIdx.x >> 1;

    const XWT*  __restrict__ xw = dir ? xw_b : xw_f;
    const float* __restrict__ Wh = dir ? Wh_b : Wh_f;
    const int col_off = dir ? HID : 0;

    h_lds[tid] = 0.0f;
    float c = 0.0f;
    __syncthreads();

    const float* wbase = Wh + 4 * tid;
    float* outb = out + (size_t)b * TSTEPS * OUTW + col_off;

    for (int s = 0; s < TSTEPS; ++s) {
        const int t = dir ? (TSTEPS - 1 - s) : s;

        float4 acc;
        {
            const XWT* xp = xw + ((size_t)t * BATCH + b) * G4 + 4 * tid;
            if constexpr (sizeof(XWT) == 4) {
                acc = *(const float4*)xp;
            } else {
                uint2 u = *(const uint2*)xp;
                acc.x = __uint_as_float(u.x << 16);
                acc.y = __uint_as_float(u.x & 0xffff0000u);
                acc.z = __uint_as_float(u.y << 16);
                acc.w = __uint_as_float(u.y & 0xffff0000u);
            }
        }

        const float* wp = wbase;
        #pragma unroll 2
        for (int k = 0; k < HID; k += 4) {
            float4 hk = *(const float4*)&h_lds[k];
            float4 w0 = *(const float4*)(wp);
            float4 w1 = *(const float4*)(wp + G4);
            float4 w2 = *(const float4*)(wp + 2 * G4);
            float4 w3 = *(const float4*)(wp + 3 * G4);
            acc.x = fmaf(hk.x, w0.x, acc.x); acc.y = fmaf(hk.x, w0.y, acc.y);
            acc.z = fmaf(hk.x, w0.z, acc.z); acc.w = fmaf(hk.x, w0.w, acc.w);
            acc.x = fmaf(hk.y, w1.x, acc.x); acc.y = fmaf(hk.y, w1.y, acc.y);
            acc.z = fmaf(hk.y, w1.z, acc.z); acc.w = fmaf(hk.y, w1.w, acc.w);
            acc.x = fmaf(hk.z, w2.x, acc.x); acc.y = fmaf(hk.z, w2.y, acc.y);
            acc.z = fmaf(hk.z, w2.z, acc.z); acc.w = fmaf(hk.z, w2.w, acc.w);
            acc.x = fmaf(hk.w, w3.x, acc.x); acc.y = fmaf(hk.w, w3.y, acc.y);
            acc.z = fmaf(hk.w, w3.z, acc.z); acc.w = fmaf(hk.w, w3.w, acc.w);
            wp += 4 * G4;
        }

        *(float4*)&z_lds[4 * tid] = acc;
        __syncthreads();

        {
            float zi = z_lds[tid];
            float zf = z_lds[tid + HID];
            float zg = z_lds[tid + 2 * HID];
            float zo = z_lds[tid + 3 * HID];
            float ig = sigf(zi);
            float fg = sigf(zf);
            float gg = tanhf_fast(zg);
            float og = sigf(zo);
            c = fmaf(fg, c, ig * gg);
            float h = og * tanhf_fast(c);
            h_lds[tid] = h;
            outb[(size_t)t * OUTW + tid] = h;
        }
        __syncthreads();
    }
}

extern "C" void kernel_launch(void* const* d_in, const int* in_sizes, int n_in,
                              void* d_out, int out_size, void* d_ws, size_t ws_size,
                              hipStream_t stream)
{
    const float* x     = (const float*)d_in[0];
    const float* Wi_f0 = (const float*)d_in[1];
    const float* Wh_f0 = (const float*)d_in[2];
    const float* b_f0  = (const float*)d_in[3];
    const float* Wi_b0 = (const float*)d_in[4];
    const float* Wh_b0 = (const float*)d_in[5];
    const float* b_b0  = (const float*)d_in[6];
    const float* Wi_f1 = (const float*)d_in[7];
    const float* Wh_f1 = (const float*)d_in[8];
    const float* b_f1  = (const float*)d_in[9];
    const float* Wi_b1 = (const float*)d_in[10];
    const float* Wh_b1 = (const float*)d_in[11];
    const float* b_b1  = (const float*)d_in[12];
    float* out = (float*)d_out;

    const size_t xw_elems = (size_t)TSTEPS * BATCH * G4;   // 33,554,432 per direction

    dim3 ggrid(G4 / 128, (TSTEPS * BATCH) / 128);          // (16, 128)
    dim3 gblock(256);
    dim3 sgrid(2 * BATCH);                                  // 64 blocks: (b, dir)
    dim3 sblock(512);

    if (ws_size >= 2 * xw_elems * sizeof(float)) {
        // fp32 xw buffers (exact path)
        float* xwf = (float*)d_ws;
        float* xwb = xwf + xw_elems;
        gemm_xw<float><<<ggrid, gblock, 0, stream>>>(x, 256, Wi_f0, b_f0, xwf);
        gemm_xw<float><<<ggrid, gblock, 0, stream>>>(x, 256, Wi_b0, b_b0, xwb);
        lstm_scan<float><<<sgrid, sblock, 0, stream>>>(xwf, xwb, Wh_f0, Wh_b0, out);
        // layer-1 GEMMs read d_out (layer-0 hidden) BEFORE the layer-1 scan overwrites it
        gemm_xw<float><<<ggrid, gblock, 0, stream>>>(out, 1024, Wi_f1, b_f1, xwf);
        gemm_xw<float><<<ggrid, gblock, 0, stream>>>(out, 1024, Wi_b1, b_b1, xwb);
        lstm_scan<float><<<sgrid, sblock, 0, stream>>>(xwf, xwb, Wh_f1, Wh_b1, out);
    } else {
        // bf16 xw buffers (134 MB) — preactivation quantization ~2e-3, well under threshold
        unsigned short* xwf = (unsigned short*)d_ws;
        unsigned short* xwb = xwf + xw_elems;
        gemm_xw<unsigned short><<<ggrid, gblock, 0, stream>>>(x, 256, Wi_f0, b_f0, xwf);
        gemm_xw<unsigned short><<<ggrid, gblock, 0, stream>>>(x, 256, Wi_b0, b_b0, xwb);
        lstm_scan<unsigned short><<<sgrid, sblock, 0, stream>>>(xwf, xwb, Wh_f0, Wh_b0, out);
        gemm_xw<unsigned short><<<ggrid, gblock, 0, stream>>>(out, 1024, Wi_f1, b_f1, xwf);
        gemm_xw<unsigned short><<<ggrid, gblock, 0, stream>>>(out, 1024, Wi_b1, b_b1, xwb);
        lstm_scan<unsigned short><<<sgrid, sblock, 0, stream>>>(xwf, xwb, Wh_f1, Wh_b1, out);
    }
}

// Round 2
// 23617.332 us; speedup vs baseline: 1.4845x; 1.4845x over previous
//
#include <hip/hip_runtime.h>
#include <stdint.h>

#define TSTEPS 512
#define BATCH  32
#define HID    512
#define G4     2048   // 4*HID gate width
#define OUTW   1024   // 2*HID output width

#define NBLK_DIR 64   // blocks per direction
#define HC       8    // h-columns owned per block
#define ZC       32   // z-columns per block (4 gates x HC)
#define ZROW     36   // padded z row stride (avoids gate-read conflicts)

__device__ __forceinline__ float sigf(float x) { return 1.0f / (1.0f + __expf(-x)); }
__device__ __forceinline__ float tanhf_fast(float x) { return 2.0f / (1.0f + __expf(-2.0f * x)) - 1.0f; }

__device__ __forceinline__ unsigned short f2bf(float f) {
    unsigned int u = __float_as_uint(f);
    u += 0x7fffu + ((u >> 16) & 1u);
    return (unsigned short)(u >> 16);
}
__device__ __forceinline__ float bf2f(unsigned short u) {
    return __uint_as_float((unsigned int)u << 16);
}

// ---------------------------------------------------------------------------
// Input-projection GEMM: xw[m, n] = sum_k X[b=(m&31), t=(m>>5), k]*W[k,n] + bias[n]
// X logical [32, 512, K] row-major; xw row m = t*32 + b; M=16384, N=2048. bf16 out.
// ---------------------------------------------------------------------------
__global__ __launch_bounds__(256) void gemm_xw(
    const float* __restrict__ X, int K,
    const float* __restrict__ W,
    const float* __restrict__ bias,
    unsigned short* __restrict__ XW)
{
    __shared__ float As[16][132];
    __shared__ float Bs[16][132];
    const int tid = threadIdx.x;
    const int n0 = blockIdx.x * 128;
    const int m0 = blockIdx.y * 128;
    const int tx = tid & 15;
    const int ty = tid >> 4;

    const int mA = tid >> 1;
    const int kA = (tid & 1) * 8;
    const int mg = m0 + mA;
    const float* arow = X + (size_t)(mg & 31) * ((size_t)TSTEPS * K) + (size_t)(mg >> 5) * K;

    const int kB = tid >> 4;
    const int nB = (tid & 15) * 8;
    const float* bptr = W + (size_t)kB * G4 + n0 + nB;

    float c[8][8];
    #pragma unroll
    for (int i = 0; i < 8; ++i)
        #pragma unroll
        for (int j = 0; j < 8; ++j) c[i][j] = 0.0f;

    for (int k0 = 0; k0 < K; k0 += 16) {
        float4 a0 = *(const float4*)(arow + k0 + kA);
        float4 a1 = *(const float4*)(arow + k0 + kA + 4);
        float4 b0 = *(const float4*)(bptr + (size_t)k0 * G4);
        float4 b1 = *(const float4*)(bptr + (size_t)k0 * G4 + 4);
        __syncthreads();
        As[kA + 0][mA] = a0.x; As[kA + 1][mA] = a0.y;
        As[kA + 2][mA] = a0.z; As[kA + 3][mA] = a0.w;
        As[kA + 4][mA] = a1.x; As[kA + 5][mA] = a1.y;
        As[kA + 6][mA] = a1.z; As[kA + 7][mA] = a1.w;
        *(float4*)&Bs[kB][nB]     = b0;
        *(float4*)&Bs[kB][nB + 4] = b1;
        __syncthreads();
        #pragma unroll
        for (int kk = 0; kk < 16; ++kk) {
            float4 av0 = *(const float4*)&As[kk][ty * 8];
            float4 av1 = *(const float4*)&As[kk][ty * 8 + 4];
            float4 bv0 = *(const float4*)&Bs[kk][tx * 8];
            float4 bv1 = *(const float4*)&Bs[kk][tx * 8 + 4];
            float a[8]  = {av0.x, av0.y, av0.z, av0.w, av1.x, av1.y, av1.z, av1.w};
            float bb[8] = {bv0.x, bv0.y, bv0.z, bv0.w, bv1.x, bv1.y, bv1.z, bv1.w};
            #pragma unroll
            for (int i = 0; i < 8; ++i)
                #pragma unroll
                for (int j = 0; j < 8; ++j)
                    c[i][j] = fmaf(a[i], bb[j], c[i][j]);
        }
    }

    float bn[8];
    #pragma unroll
    for (int j = 0; j < 8; ++j) bn[j] = bias[n0 + tx * 8 + j];

    #pragma unroll
    for (int i = 0; i < 8; ++i) {
        const int m = m0 + ty * 8 + i;
        unsigned short* orow = XW + (size_t)m * G4 + n0 + tx * 8;
        #pragma unroll
        for (int j = 0; j < 8; ++j) orow[j] = f2bf(c[i][j] + bn[j]);
    }
}

// ---------------------------------------------------------------------------
// Distributed recurrent scan.
// Grid = 128 blocks: dir = blockIdx.x & 1, p = blockIdx.x >> 1 (0..63).
// Block owns h-cols [p*8, p*8+8) -> z-cols {p*8+j + 512*g}.
// Wh column slice (32 zc x 512 k fp32, transposed + swizzled) lives in LDS for
// the whole scan. h[32,512] exchanged via global double buffer + per-step
// atomic flag barrier (all 128 blocks co-resident: 1 block/CU by LDS).
// ---------------------------------------------------------------------------
__global__ __launch_bounds__(512, 1) void lstm_scan2(
    const unsigned short* __restrict__ xw_f,  // [T, B, 2048] bf16
    const unsigned short* __restrict__ xw_b,
    const float* __restrict__ Wh_f,           // [512, 2048]
    const float* __restrict__ Wh_b,
    float* __restrict__ out,                  // [B, T, 1024]
    float* __restrict__ hbuf,                 // [2 dir][2 parity][32][512] f32
    int*   __restrict__ flags)                // [2 dir][TSTEPS]
{
    extern __shared__ float smem[];
    float* Whs   = smem;                       // 32*512 = 16384 f (64 KB)
    float* h_lds = smem + ZC * HID;            // 32*512 = 16384 f (64 KB)
    float* z_lds = smem + 2 * ZC * HID;        // 32*36 f (~4.6 KB)

    const int tid = threadIdx.x;
    const int dir = blockIdx.x & 1;
    const int p   = blockIdx.x >> 1;

    const unsigned short* __restrict__ xw = dir ? xw_b : xw_f;
    const float* __restrict__ Wh = dir ? Wh_b : Wh_f;
    float* hb  = hbuf + (size_t)dir * (2 * BATCH * HID);
    int*   flg = flags + dir * TSTEPS;

    // One-time Wh slice load: transposed [zc][k], XOR-swizzled (elem ^= (zc&7)<<2)
    {
        const int j  = tid & 7;
        const int g  = (tid >> 3) & 3;
        const int ks = tid >> 5;              // 0..15
        const int zc = g * 8 + j;
        const int col = p * 8 + j + 512 * g;
        const int sw = (zc & 7) << 2;
        #pragma unroll 4
        for (int kk = 0; kk < 32; ++kk) {
            const int k = ks * 32 + kk;
            Whs[zc * HID + (k ^ sw)] = Wh[(size_t)k * G4 + col];
        }
    }
    float c_reg = 0.0f;                        // owned by tid < 256: (b = tid>>3, j = tid&7)
    __syncthreads();

    const int zc  = tid & 31;
    const int bp  = tid >> 5;                  // 0..15
    const int b0  = bp, b1 = bp + 16;
    const int sw  = (zc & 7) << 2;
    const float* wrow = &Whs[zc * HID];
    const int gcol = p * 8 + (zc & 7) + 512 * (zc >> 3);

    const int gb = tid >> 3;                   // gate-thread batch (tid<256)
    const int gj = tid & 7;                    // gate-thread h-col within block
    float* outg = out + (size_t)gb * TSTEPS * OUTW + dir * HID + p * 8 + gj;

    for (int s = 0; s < TSTEPS; ++s) {
        const int t = dir ? (TSTEPS - 1 - s) : s;

        // xw contribution — issue early (hides under the spin)
        float acc0, acc1;
        {
            const unsigned short* xp = xw + (size_t)t * BATCH * G4 + gcol;
            acc0 = bf2f(xp[(size_t)b0 * G4]);
            acc1 = bf2f(xp[(size_t)b1 * G4]);
        }

        if (s > 0) {
            if (tid == 0) {
                while (__hip_atomic_load(&flg[s - 1], __ATOMIC_ACQUIRE,
                                         __HIP_MEMORY_SCOPE_AGENT) < NBLK_DIR) { }
            }
            __syncthreads();
            // stage h[32,512] from global double buffer into LDS (coalesced)
            {
                const float4* src = (const float4*)(hb + ((s - 1) & 1) * (BATCH * HID));
                float4* dst = (float4*)h_lds;
                #pragma unroll
                for (int i = 0; i < 8; ++i) dst[tid + i * 512] = src[tid + i * 512];
            }
            __syncthreads();

            const float* hr0 = &h_lds[b0 * HID];
            const float* hr1 = &h_lds[b1 * HID];
            float s0a = 0.f, s0b = 0.f, s1a = 0.f, s1b = 0.f;
            #pragma unroll 2
            for (int k4 = 0; k4 < 128; k4 += 2) {
                float4 w0 = *(const float4*)&wrow[(k4 * 4) ^ sw];
                float4 a0 = *(const float4*)&hr0[k4 * 4];
                float4 q0 = *(const float4*)&hr1[k4 * 4];
                float4 w1 = *(const float4*)&wrow[((k4 + 1) * 4) ^ sw];
                float4 a1 = *(const float4*)&hr0[(k4 + 1) * 4];
                float4 q1 = *(const float4*)&hr1[(k4 + 1) * 4];
                s0a = fmaf(w0.x, a0.x, s0a); s0a = fmaf(w0.y, a0.y, s0a);
                s0a = fmaf(w0.z, a0.z, s0a); s0a = fmaf(w0.w, a0.w, s0a);
                s1a = fmaf(w0.x, q0.x, s1a); s1a = fmaf(w0.y, q0.y, s1a);
                s1a = fmaf(w0.z, q0.z, s1a); s1a = fmaf(w0.w, q0.w, s1a);
                s0b = fmaf(w1.x, a1.x, s0b); s0b = fmaf(w1.y, a1.y, s0b);
                s0b = fmaf(w1.z, a1.z, s0b); s0b = fmaf(w1.w, a1.w, s0b);
                s1b = fmaf(w1.x, q1.x, s1b); s1b = fmaf(w1.y, q1.y, s1b);
                s1b = fmaf(w1.z, q1.z, s1b); s1b = fmaf(w1.w, q1.w, s1b);
            }
            acc0 += s0a + s0b;
            acc1 += s1a + s1b;
        }

        z_lds[b0 * ZROW + zc] = acc0;
        z_lds[b1 * ZROW + zc] = acc1;
        __syncthreads();

        if (tid < 256) {
            const float* zr = &z_lds[gb * ZROW];
            float zi = zr[gj];
            float zf = zr[gj + 8];
            float zg = zr[gj + 16];
            float zo = zr[gj + 24];
            float ig = sigf(zi);
            float fg = sigf(zf);
            float gg = tanhf_fast(zg);
            float og = sigf(zo);
            c_reg = fmaf(fg, c_reg, ig * gg);
            float h = og * tanhf_fast(c_reg);
            hb[(s & 1) * (BATCH * HID) + gb * HID + p * 8 + gj] = h;
            outg[(size_t)t * OUTW] = h;
        }
        __syncthreads();   // all writes issued before release
        if (tid == 0) {
            __threadfence();
            __hip_atomic_fetch_add(&flg[s], 1, __ATOMIC_RELEASE, __HIP_MEMORY_SCOPE_AGENT);
        }
        // next iteration's spin + syncthreads protects h_lds / z_lds reuse
    }
}

extern "C" void kernel_launch(void* const* d_in, const int* in_sizes, int n_in,
                              void* d_out, int out_size, void* d_ws, size_t ws_size,
                              hipStream_t stream)
{
    const float* x     = (const float*)d_in[0];
    const float* Wi_f0 = (const float*)d_in[1];
    const float* Wh_f0 = (const float*)d_in[2];
    const float* b_f0  = (const float*)d_in[3];
    const float* Wi_b0 = (const float*)d_in[4];
    const float* Wh_b0 = (const float*)d_in[5];
    const float* b_b0  = (const float*)d_in[6];
    const float* Wi_f1 = (const float*)d_in[7];
    const float* Wh_f1 = (const float*)d_in[8];
    const float* b_f1  = (const float*)d_in[9];
    const float* Wi_b1 = (const float*)d_in[10];
    const float* Wh_b1 = (const float*)d_in[11];
    const float* b_b1  = (const float*)d_in[12];
    float* out = (float*)d_out;

    const size_t xw_elems = (size_t)TSTEPS * BATCH * G4;        // 33,554,432
    unsigned short* xwf = (unsigned short*)d_ws;
    unsigned short* xwb = xwf + xw_elems;
    char* tail  = (char*)d_ws + 2 * xw_elems * sizeof(unsigned short); // 128 MiB
    float* hbuf = (float*)tail;                                  // 256 KiB
    int* flags  = (int*)(tail + 2 * 2 * BATCH * HID * sizeof(float));
    // flags: [layer][dir][TSTEPS] = 2*2*512 ints = 8 KiB

    hipMemsetAsync(flags, 0, 2 * 2 * TSTEPS * sizeof(int), stream);

    dim3 ggrid(G4 / 128, (TSTEPS * BATCH) / 128);
    dim3 gblock(256);
    dim3 sgrid(2 * NBLK_DIR);   // 128 blocks
    dim3 sblock(512);
    const size_t smem = (2 * ZC * HID + BATCH * ZROW) * sizeof(float); // ~135.7 KB

    // layer 0
    gemm_xw<<<ggrid, gblock, 0, stream>>>(x, 256, Wi_f0, b_f0, xwf);
    gemm_xw<<<ggrid, gblock, 0, stream>>>(x, 256, Wi_b0, b_b0, xwb);
    lstm_scan2<<<sgrid, sblock, smem, stream>>>(xwf, xwb, Wh_f0, Wh_b0, out,
                                                hbuf, flags);
    // layer 1 (GEMMs read d_out before the layer-1 scan overwrites it)
    gemm_xw<<<ggrid, gblock, 0, stream>>>(out, 1024, Wi_f1, b_f1, xwf);
    gemm_xw<<<ggrid, gblock, 0, stream>>>(out, 1024, Wi_b1, b_b1, xwb);
    lstm_scan2<<<sgrid, sblock, smem, stream>>>(xwf, xwb, Wh_f1, Wh_b1, out,
                                                hbuf, flags + 2 * TSTEPS);
}

// Round 3
// 14251.538 us; speedup vs baseline: 2.4600x; 1.6572x over previous
//
#include <hip/hip_runtime.h>
#include <stdint.h>

#define TSTEPS 512
#define BATCH  32
#define HID    512
#define G4     2048   // 4*HID gate width
#define OUTW   1024   // 2*HID output width
#define MTOT   (TSTEPS * BATCH)   // 16384 rows, m = t*32 + b

#define NBLK_DIR 64   // blocks per direction
#define ZC       32   // z-columns per block (4 gates x 8 h-cols)
#define ZROW     36   // padded z row stride

__device__ __forceinline__ float sigf(float x) { return 1.0f / (1.0f + __expf(-x)); }
__device__ __forceinline__ float tanhf_fast(float x) { return 2.0f / (1.0f + __expf(-2.0f * x)) - 1.0f; }

__device__ __forceinline__ unsigned short f2bf(float f) {
    unsigned int u = __float_as_uint(f);
    u += 0x7fffu + ((u >> 16) & 1u);
    return (unsigned short)(u >> 16);
}
__device__ __forceinline__ float bf2f(unsigned short u) {
    return __uint_as_float((unsigned int)u << 16);
}

// ---------------------------------------------------------------------------
// Input-projection GEMM, TRANSPOSED output: XWt[n][m] (bf16), m = t*32 + b.
// xw[m,n] = sum_k X[b=(m&31), t=(m>>5), k] * W[k,n] + bias[n]; M=16384, N=2048.
// ---------------------------------------------------------------------------
__global__ __launch_bounds__(256) void gemm_xw(
    const float* __restrict__ X, int K,
    const float* __restrict__ W,
    const float* __restrict__ bias,
    unsigned short* __restrict__ XWt)
{
    __shared__ float As[16][132];
    __shared__ float Bs[16][132];
    const int tid = threadIdx.x;
    const int n0 = blockIdx.x * 128;
    const int m0 = blockIdx.y * 128;
    const int tx = tid & 15;
    const int ty = tid >> 4;

    const int mA = tid >> 1;
    const int kA = (tid & 1) * 8;
    const int mg = m0 + mA;
    const float* arow = X + (size_t)(mg & 31) * ((size_t)TSTEPS * K) + (size_t)(mg >> 5) * K;

    const int kB = tid >> 4;
    const int nB = (tid & 15) * 8;
    const float* bptr = W + (size_t)kB * G4 + n0 + nB;

    float c[8][8];
    #pragma unroll
    for (int i = 0; i < 8; ++i)
        #pragma unroll
        for (int j = 0; j < 8; ++j) c[i][j] = 0.0f;

    for (int k0 = 0; k0 < K; k0 += 16) {
        float4 a0 = *(const float4*)(arow + k0 + kA);
        float4 a1 = *(const float4*)(arow + k0 + kA + 4);
        float4 b0 = *(const float4*)(bptr + (size_t)k0 * G4);
        float4 b1 = *(const float4*)(bptr + (size_t)k0 * G4 + 4);
        __syncthreads();
        As[kA + 0][mA] = a0.x; As[kA + 1][mA] = a0.y;
        As[kA + 2][mA] = a0.z; As[kA + 3][mA] = a0.w;
        As[kA + 4][mA] = a1.x; As[kA + 5][mA] = a1.y;
        As[kA + 6][mA] = a1.z; As[kA + 7][mA] = a1.w;
        *(float4*)&Bs[kB][nB]     = b0;
        *(float4*)&Bs[kB][nB + 4] = b1;
        __syncthreads();
        #pragma unroll
        for (int kk = 0; kk < 16; ++kk) {
            float4 av0 = *(const float4*)&As[kk][ty * 8];
            float4 av1 = *(const float4*)&As[kk][ty * 8 + 4];
            float4 bv0 = *(const float4*)&Bs[kk][tx * 8];
            float4 bv1 = *(const float4*)&Bs[kk][tx * 8 + 4];
            float a[8]  = {av0.x, av0.y, av0.z, av0.w, av1.x, av1.y, av1.z, av1.w};
            float bb[8] = {bv0.x, bv0.y, bv0.z, bv0.w, bv1.x, bv1.y, bv1.z, bv1.w};
            #pragma unroll
            for (int i = 0; i < 8; ++i)
                #pragma unroll
                for (int j = 0; j < 8; ++j)
                    c[i][j] = fmaf(a[i], bb[j], c[i][j]);
        }
    }

    float bn[8];
    #pragma unroll
    for (int j = 0; j < 8; ++j) bn[j] = bias[n0 + tx * 8 + j];

    // packed 16B stores: 8 consecutive m (bf16) per column n
    #pragma unroll
    for (int j = 0; j < 8; ++j) {
        const int n = n0 + tx * 8 + j;
        unsigned int w0 = (unsigned)f2bf(c[0][j] + bn[j]) | ((unsigned)f2bf(c[1][j] + bn[j]) << 16);
        unsigned int w1 = (unsigned)f2bf(c[2][j] + bn[j]) | ((unsigned)f2bf(c[3][j] + bn[j]) << 16);
        unsigned int w2 = (unsigned)f2bf(c[4][j] + bn[j]) | ((unsigned)f2bf(c[5][j] + bn[j]) << 16);
        unsigned int w3 = (unsigned)f2bf(c[6][j] + bn[j]) | ((unsigned)f2bf(c[7][j] + bn[j]) << 16);
        uint4 pk; pk.x = w0; pk.y = w1; pk.z = w2; pk.w = w3;
        *(uint4*)(XWt + (size_t)n * MTOT + (m0 + ty * 8)) = pk;
    }
}

// ---------------------------------------------------------------------------
// Distributed recurrent scan, MALL-based h exchange (no L2 flush/invalidate).
// Grid = 128 blocks: dir = blockIdx.x & 1, p = blockIdx.x >> 1.
// Block owns h-cols [p*8, p*8+8) -> z-cols {p*8+j + 512*g}.
// ---------------------------------------------------------------------------
__global__ __launch_bounds__(512, 1) void lstm_scan3(
    const unsigned short* __restrict__ xw_f,  // [G4][MTOT] bf16, transposed
    const unsigned short* __restrict__ xw_b,
    const float* __restrict__ Wh_f,           // [512, 2048]
    const float* __restrict__ Wh_b,
    float* __restrict__ out,                  // [B, T, 1024]
    float* __restrict__ hbuf,                 // [dir][2 parity][32][512] f32
    int*   __restrict__ flags)                // [dir][TSTEPS]
{
    extern __shared__ float smem[];
    float* Whs   = smem;                       // 32*512 f (64 KB)
    float* h_lds = smem + ZC * HID;            // 32*512 f (64 KB)
    float* z_lds = smem + 2 * ZC * HID;        // 32*36 f (~4.6 KB)

    const int tid = threadIdx.x;
    const int dir = blockIdx.x & 1;
    const int p   = blockIdx.x >> 1;

    const unsigned short* __restrict__ xw = dir ? xw_b : xw_f;
    const float* __restrict__ Wh = dir ? Wh_b : Wh_f;
    float* hb  = hbuf + (size_t)dir * (2 * BATCH * HID);
    int*   flg = flags + dir * TSTEPS;

    // One-time Wh slice load: transposed [zc][k], XOR-swizzled
    {
        const int j  = tid & 7;
        const int g  = (tid >> 3) & 3;
        const int ks = tid >> 5;              // 0..15
        const int zcl = g * 8 + j;
        const int col = p * 8 + j + 512 * g;
        const int swl = (zcl & 7) << 2;
        #pragma unroll 4
        for (int kk = 0; kk < 32; ++kk) {
            const int k = ks * 32 + kk;
            Whs[zcl * HID + (k ^ swl)] = Wh[(size_t)k * G4 + col];
        }
    }
    float c_reg = 0.0f;
    __syncthreads();

    const int zc  = tid & 31;
    const int bp  = tid >> 5;                  // 0..15
    const int b0  = bp, b1 = bp + 16;
    const int sw  = (zc & 7) << 2;
    const float* wrow = &Whs[zc * HID];
    const int gcol = p * 8 + (zc & 7) + 512 * (zc >> 3);
    const unsigned short* xcol = xw + (size_t)gcol * MTOT;

    const int gb = tid >> 3;                   // gate-thread batch (tid<256)
    const int gj = tid & 7;                    // gate-thread h-col within block
    float* outg = out + (size_t)gb * TSTEPS * OUTW + dir * HID + p * 8 + gj;

    for (int s = 0; s < TSTEPS; ++s) {
        const int t = dir ? (TSTEPS - 1 - s) : s;

        // xw contribution (cached loads; L2 stays warm — no invalidates anywhere)
        float acc0 = bf2f(xcol[t * 32 + b0]);
        float acc1 = bf2f(xcol[t * 32 + b1]);

        if (s > 0) {
            if (tid == 0) {
                while (__hip_atomic_load(&flg[s - 1], __ATOMIC_RELAXED,
                                         __HIP_MEMORY_SCOPE_AGENT) < NBLK_DIR) { }
            }
            __syncthreads();
            // stage h[32,512] from MALL (L2-bypass dwordx4), then into LDS
            {
                const float* src = hb + ((s - 1) & 1) * (BATCH * HID);
                float4 hv[8];
                #pragma unroll
                for (int i = 0; i < 8; ++i) {
                    const float* ap = src + (size_t)(tid + i * 512) * 4;
                    asm volatile("global_load_dwordx4 %0, %1, off sc0 sc1"
                                 : "=v"(hv[i]) : "v"(ap) : "memory");
                }
                asm volatile("s_waitcnt vmcnt(0)" ::: "memory");
                __builtin_amdgcn_sched_barrier(0);
                #pragma unroll
                for (int i = 0; i < 8; ++i)
                    *(float4*)&h_lds[(size_t)(tid + i * 512) * 4] = hv[i];
            }
            __syncthreads();

            const float* hr0 = &h_lds[b0 * HID];
            const float* hr1 = &h_lds[b1 * HID];
            float s0a = 0.f, s0b = 0.f, s1a = 0.f, s1b = 0.f;
            #pragma unroll 2
            for (int k4 = 0; k4 < 128; k4 += 2) {
                float4 w0 = *(const float4*)&wrow[(k4 * 4) ^ sw];
                float4 a0 = *(const float4*)&hr0[k4 * 4];
                float4 q0 = *(const float4*)&hr1[k4 * 4];
                float4 w1 = *(const float4*)&wrow[((k4 + 1) * 4) ^ sw];
                float4 a1 = *(const float4*)&hr0[(k4 + 1) * 4];
                float4 q1 = *(const float4*)&hr1[(k4 + 1) * 4];
                s0a = fmaf(w0.x, a0.x, s0a); s0a = fmaf(w0.y, a0.y, s0a);
                s0a = fmaf(w0.z, a0.z, s0a); s0a = fmaf(w0.w, a0.w, s0a);
                s1a = fmaf(w0.x, q0.x, s1a); s1a = fmaf(w0.y, q0.y, s1a);
                s1a = fmaf(w0.z, q0.z, s1a); s1a = fmaf(w0.w, q0.w, s1a);
                s0b = fmaf(w1.x, a1.x, s0b); s0b = fmaf(w1.y, a1.y, s0b);
                s0b = fmaf(w1.z, a1.z, s0b); s0b = fmaf(w1.w, a1.w, s0b);
                s1b = fmaf(w1.x, q1.x, s1b); s1b = fmaf(w1.y, q1.y, s1b);
                s1b = fmaf(w1.z, q1.z, s1b); s1b = fmaf(w1.w, q1.w, s1b);
            }
            acc0 += s0a + s0b;
            acc1 += s1a + s1b;
        }

        z_lds[b0 * ZROW + zc] = acc0;
        z_lds[b1 * ZROW + zc] = acc1;
        __syncthreads();

        float hnew = 0.0f;
        if (tid < 256) {
            const float* zr = &z_lds[gb * ZROW];
            float zi = zr[gj];
            float zf = zr[gj + 8];
            float zg = zr[gj + 16];
            float zo = zr[gj + 24];
            float ig = sigf(zi);
            float fg = sigf(zf);
            float gg = tanhf_fast(zg);
            float og = sigf(zo);
            c_reg = fmaf(fg, c_reg, ig * gg);
            hnew = og * tanhf_fast(c_reg);
            // L2-bypass store -> MALL (coherence point), no fence needed
            __hip_atomic_store(hb + (s & 1) * (BATCH * HID) + gb * HID + p * 8 + gj,
                               hnew, __ATOMIC_RELAXED, __HIP_MEMORY_SCOPE_AGENT);
        }
        __syncthreads();   // implicit s_waitcnt vmcnt(0) drains the h stores
        if (tid == 0) {
            asm volatile("s_waitcnt vmcnt(0)" ::: "memory");
            __hip_atomic_fetch_add(&flg[s], 1, __ATOMIC_RELAXED, __HIP_MEMORY_SCOPE_AGENT);
        }
        if (tid < 256) outg[(size_t)t * OUTW] = hnew;   // off the critical path
    }
}

extern "C" void kernel_launch(void* const* d_in, const int* in_sizes, int n_in,
                              void* d_out, int out_size, void* d_ws, size_t ws_size,
                              hipStream_t stream)
{
    const float* x     = (const float*)d_in[0];
    const float* Wi_f0 = (const float*)d_in[1];
    const float* Wh_f0 = (const float*)d_in[2];
    const float* b_f0  = (const float*)d_in[3];
    const float* Wi_b0 = (const float*)d_in[4];
    const float* Wh_b0 = (const float*)d_in[5];
    const float* b_b0  = (const float*)d_in[6];
    const float* Wi_f1 = (const float*)d_in[7];
    const float* Wh_f1 = (const float*)d_in[8];
    const float* b_f1  = (const float*)d_in[9];
    const float* Wi_b1 = (const float*)d_in[10];
    const float* Wh_b1 = (const float*)d_in[11];
    const float* b_b1  = (const float*)d_in[12];
    float* out = (float*)d_out;

    const size_t xw_elems = (size_t)MTOT * G4;                   // 33,554,432
    unsigned short* xwf = (unsigned short*)d_ws;
    unsigned short* xwb = xwf + xw_elems;
    char* tail  = (char*)d_ws + 2 * xw_elems * sizeof(unsigned short); // 128 MiB
    float* hbuf = (float*)tail;                                  // 2dir*2par*32*512 f
    int* flags  = (int*)(tail + 2 * 2 * BATCH * HID * sizeof(float));
    // flags: [layer][dir][TSTEPS] = 2*2*512 ints

    hipMemsetAsync(flags, 0, 2 * 2 * TSTEPS * sizeof(int), stream);

    dim3 ggrid(G4 / 128, MTOT / 128);
    dim3 gblock(256);
    dim3 sgrid(2 * NBLK_DIR);   // 128 blocks
    dim3 sblock(512);
    const size_t smem = (2 * ZC * HID + BATCH * ZROW) * sizeof(float); // ~135.7 KB

    // layer 0
    gemm_xw<<<ggrid, gblock, 0, stream>>>(x, 256, Wi_f0, b_f0, xwf);
    gemm_xw<<<ggrid, gblock, 0, stream>>>(x, 256, Wi_b0, b_b0, xwb);
    lstm_scan3<<<sgrid, sblock, smem, stream>>>(xwf, xwb, Wh_f0, Wh_b0, out,
                                                hbuf, flags);
    // layer 1 (GEMMs read d_out before the layer-1 scan overwrites it)
    gemm_xw<<<ggrid, gblock, 0, stream>>>(out, 1024, Wi_f1, b_f1, xwf);
    gemm_xw<<<ggrid, gblock, 0, stream>>>(out, 1024, Wi_b1, b_b1, xwb);
    lstm_scan3<<<sgrid, sblock, smem, stream>>>(xwf, xwb, Wh_f1, Wh_b1, out,
                                                hbuf, flags + 2 * TSTEPS);
}

// Round 5
// 9847.975 us; speedup vs baseline: 3.5600x; 1.4472x over previous
//
#include <hip/hip_runtime.h>
#include <stdint.h>

#define TSTEPS 512
#define BATCH  32
#define HID    512
#define G4     2048
#define OUTW   1024
#define MTOT   (TSTEPS * BATCH)   // 16384, m = t*32 + b

#define NBLK_DIR 64   // blocks per direction
typedef __attribute__((ext_vector_type(8))) short bf16x8;
typedef __attribute__((ext_vector_type(4))) float f32x4;

__device__ __forceinline__ float sigf(float x) { return 1.0f / (1.0f + __expf(-x)); }
__device__ __forceinline__ float tanhf_fast(float x) { return 2.0f / (1.0f + __expf(-2.0f * x)) - 1.0f; }

__device__ __forceinline__ unsigned short f2bf(float f) {
    unsigned int u = __float_as_uint(f);
    u += 0x7fffu + ((u >> 16) & 1u);
    return (unsigned short)(u >> 16);
}
__device__ __forceinline__ float bf2f(unsigned short u) {
    return __uint_as_float((unsigned int)u << 16);
}

// ---------------------------------------------------------------------------
// Input-projection GEMM, TRANSPOSED output: XWt[n][m] (bf16), m = t*32 + b.
// ---------------------------------------------------------------------------
__global__ __launch_bounds__(256) void gemm_xw(
    const float* __restrict__ X, int K,
    const float* __restrict__ W,
    const float* __restrict__ bias,
    unsigned short* __restrict__ XWt)
{
    __shared__ float As[16][132];
    __shared__ float Bs[16][132];
    const int tid = threadIdx.x;
    const int n0 = blockIdx.x * 128;
    const int m0 = blockIdx.y * 128;
    const int tx = tid & 15;
    const int ty = tid >> 4;

    const int mA = tid >> 1;
    const int kA = (tid & 1) * 8;
    const int mg = m0 + mA;
    const float* arow = X + (size_t)(mg & 31) * ((size_t)TSTEPS * K) + (size_t)(mg >> 5) * K;

    const int kB = tid >> 4;
    const int nB = (tid & 15) * 8;
    const float* bptr = W + (size_t)kB * G4 + n0 + nB;

    float c[8][8];
    #pragma unroll
    for (int i = 0; i < 8; ++i)
        #pragma unroll
        for (int j = 0; j < 8; ++j) c[i][j] = 0.0f;

    for (int k0 = 0; k0 < K; k0 += 16) {
        float4 a0 = *(const float4*)(arow + k0 + kA);
        float4 a1 = *(const float4*)(arow + k0 + kA + 4);
        float4 b0 = *(const float4*)(bptr + (size_t)k0 * G4);
        float4 b1 = *(const float4*)(bptr + (size_t)k0 * G4 + 4);
        __syncthreads();
        As[kA + 0][mA] = a0.x; As[kA + 1][mA] = a0.y;
        As[kA + 2][mA] = a0.z; As[kA + 3][mA] = a0.w;
        As[kA + 4][mA] = a1.x; As[kA + 5][mA] = a1.y;
        As[kA + 6][mA] = a1.z; As[kA + 7][mA] = a1.w;
        *(float4*)&Bs[kB][nB]     = b0;
        *(float4*)&Bs[kB][nB + 4] = b1;
        __syncthreads();
        #pragma unroll
        for (int kk = 0; kk < 16; ++kk) {
            float4 av0 = *(const float4*)&As[kk][ty * 8];
            float4 av1 = *(const float4*)&As[kk][ty * 8 + 4];
            float4 bv0 = *(const float4*)&Bs[kk][tx * 8];
            float4 bv1 = *(const float4*)&Bs[kk][tx * 8 + 4];
            float a[8]  = {av0.x, av0.y, av0.z, av0.w, av1.x, av1.y, av1.z, av1.w};
            float bb[8] = {bv0.x, bv0.y, bv0.z, bv0.w, bv1.x, bv1.y, bv1.z, bv1.w};
            #pragma unroll
            for (int i = 0; i < 8; ++i)
                #pragma unroll
                for (int j = 0; j < 8; ++j)
                    c[i][j] = fmaf(a[i], bb[j], c[i][j]);
        }
    }

    float bn[8];
    #pragma unroll
    for (int j = 0; j < 8; ++j) bn[j] = bias[n0 + tx * 8 + j];

    #pragma unroll
    for (int j = 0; j < 8; ++j) {
        const int n = n0 + tx * 8 + j;
        unsigned int w0 = (unsigned)f2bf(c[0][j] + bn[j]) | ((unsigned)f2bf(c[1][j] + bn[j]) << 16);
        unsigned int w1 = (unsigned)f2bf(c[2][j] + bn[j]) | ((unsigned)f2bf(c[3][j] + bn[j]) << 16);
        unsigned int w2 = (unsigned)f2bf(c[4][j] + bn[j]) | ((unsigned)f2bf(c[5][j] + bn[j]) << 16);
        unsigned int w3 = (unsigned)f2bf(c[6][j] + bn[j]) | ((unsigned)f2bf(c[7][j] + bn[j]) << 16);
        uint4 pk; pk.x = w0; pk.y = w1; pk.z = w2; pk.w = w3;
        *(uint4*)(XWt + (size_t)n * MTOT + (m0 + ty * 8)) = pk;
    }
}

// ---------------------------------------------------------------------------
// MFMA recurrent scan. 128 blocks x 64 threads (1 wave). dir = blk&1, p = blk>>1.
// Block owns h-cols [p*8, p*8+8) -> zc 0..31, gcol = p*8 + (zc&7) + 512*(zc>>3).
// z[32b x 32zc] via 4x mfma_f32_16x16x32_bf16 tiles, K=512, 3-product hi/lo split.
// h exchanged as bf16 hi/lo planes via MALL (sc0 sc1) + per-step flag barrier.
// LDS: Wfrags 64KB | h-stage 64KB | z 4.2KB  -> 1 block/CU, 128 co-resident.
// ---------------------------------------------------------------------------
__global__ __launch_bounds__(64, 1) void lstm_scan4(
    const unsigned short* __restrict__ xw_f,  // [G4][MTOT] bf16
    const unsigned short* __restrict__ xw_b,
    const float* __restrict__ Wh_f,           // [512][2048] f32
    const float* __restrict__ Wh_b,
    float* __restrict__ out,                  // [B][T][1024] f32
    unsigned short* __restrict__ hbuf,        // [dir][parity][plane][32][512] bf16
    int* __restrict__ flags)                  // [dir][TSTEPS]
{
    extern __shared__ char smem[];
    char* WFR = smem;                 // frag: plane*32768 + (ki*2+ct)*1024 + l*16
    char* HST = smem + 65536;         // plane*32768 + b*1024 + (kbyte ^ ((b&7)<<4))
    float* ZL  = (float*)(smem + 131072);   // [32][33]

    const int l    = threadIdx.x;
    const int dir  = blockIdx.x & 1;
    const int p    = blockIdx.x >> 1;
    const int lc16 = l & 15;
    const int lq4  = l >> 4;          // 0..3
    const int lb   = l & 31;
    const int hi5  = l >> 5;
    const int l16  = l * 16;
    const int swz  = (l & 7) << 4;

    const unsigned short* __restrict__ xw = dir ? xw_b : xw_f;
    const float* __restrict__ Wh = dir ? Wh_b : Wh_f;
    char* hb   = (char*)hbuf + (size_t)dir * 131072;
    int*  flg  = flags + dir * TSTEPS;

    // ---- one-time: Wh slice -> hi/lo bf16 frags in LDS ----
    {
        #pragma unroll
        for (int ct = 0; ct < 2; ++ct) {
            const int zc  = ct * 16 + lc16;
            const int col = p * 8 + (zc & 7) + 512 * (zc >> 3);
            for (int ki = 0; ki < 16; ++ki) {
                const float* src = Wh + (size_t)(ki * 32 + lq4 * 8) * G4 + col;
                bf16x8 vh, vl;
                #pragma unroll
                for (int r = 0; r < 8; ++r) {
                    float v = src[(size_t)r * G4];
                    unsigned short h16 = f2bf(v);
                    vh[r] = (short)h16;
                    vl[r] = (short)f2bf(v - bf2f(h16));
                }
                *(bf16x8*)(WFR + (ki * 2 + ct) * 1024 + l16)         = vh;
                *(bf16x8*)(WFR + 32768 + (ki * 2 + ct) * 1024 + l16) = vl;
            }
        }
    }

    // xw column bases for this lane's two coltiles
    const int gc0 = p * 8 + (lc16 & 7) + 512 * (lc16 >> 3);
    const unsigned short* xc0 = xw + (size_t)gc0 * MTOT;
    const unsigned short* xc1 = xw + (size_t)(gc0 + 1024) * MTOT;

    float cq[4] = {0.f, 0.f, 0.f, 0.f};

    for (int s = 0; s < TSTEPS; ++s) {
        const int t = dir ? (TSTEPS - 1 - s) : s;

        // xw gate values for this lane's 16 acc elements (read-only, no ordering needed)
        const int xoff = t * 32 + lq4 * 4;
        uint2 u00 = *(const uint2*)(xc0 + xoff);        // rt0, ct0: rows lq4*4..+3
        uint2 u10 = *(const uint2*)(xc0 + xoff + 16);   // rt1, ct0
        uint2 u01 = *(const uint2*)(xc1 + xoff);        // rt0, ct1
        uint2 u11 = *(const uint2*)(xc1 + xoff + 16);   // rt1, ct1

        f32x4 acc00 = {0,0,0,0}, acc01 = {0,0,0,0}, acc10 = {0,0,0,0}, acc11 = {0,0,0,0};

        if (s > 0) {
            if (l == 0) {
                while (__hip_atomic_load(&flg[s - 1], __ATOMIC_RELAXED,
                                         __HIP_MEMORY_SCOPE_AGENT) < NBLK_DIR) { }
            }
            __builtin_amdgcn_sched_barrier(0);
            asm volatile("" ::: "memory");

            // ---- stage h planes (64KB) from MALL into swizzled LDS rows ----
            const char* hsrc = hb + ((s - 1) & 1) * 65536;
            float4 rA[8], rB[8];
#define STG_ISSUE(BUF, C) \
            _Pragma("unroll") \
            for (int jj = 0; jj < 8; ++jj) { \
                const char* sp = hsrc + ((C) * 8 + jj) * 1024 + l16; \
                asm volatile("global_load_dwordx4 %0, %1, off sc0 sc1" \
                             : "=v"(BUF[jj]) : "v"(sp) : "memory"); \
            }
#define STG_WRITE(BUF, C, N) \
            asm volatile("s_waitcnt vmcnt(" #N ")" ::: "memory"); \
            _Pragma("unroll") \
            for (int jj = 0; jj < 8; ++jj) { \
                const int i  = (C) * 8 + jj; \
                const int pl = i >> 5, b = i & 31; \
                *(float4*)(HST + pl * 32768 + b * 1024 + (l16 ^ ((b & 7) << 4))) = BUF[jj]; \
            }
            STG_ISSUE(rA, 0); STG_ISSUE(rB, 1);
            STG_WRITE(rA, 0, 8);
            STG_ISSUE(rA, 2); STG_WRITE(rB, 1, 8);
            STG_ISSUE(rB, 3); STG_WRITE(rA, 2, 8);
            STG_ISSUE(rA, 4); STG_WRITE(rB, 3, 8);
            STG_ISSUE(rB, 5); STG_WRITE(rA, 4, 8);
            STG_ISSUE(rA, 6); STG_WRITE(rB, 5, 8);
            STG_ISSUE(rB, 7); STG_WRITE(rA, 6, 8);
            STG_WRITE(rB, 7, 0);
#undef STG_ISSUE
#undef STG_WRITE

            // ---- MFMA: 16 ki x (4 A-frags + 4 B-frags + 12 mfma) ----
            #pragma unroll
            for (int ki = 0; ki < 16; ++ki) {
                const int ko = (ki * 64 + lq4 * 16) ^ swz;
                bf16x8 ah0 = *(const bf16x8*)(HST + (size_t)lc16 * 1024 + ko);
                bf16x8 ah1 = *(const bf16x8*)(HST + (size_t)(lc16 + 16) * 1024 + ko);
                bf16x8 al0 = *(const bf16x8*)(HST + 32768 + (size_t)lc16 * 1024 + ko);
                bf16x8 al1 = *(const bf16x8*)(HST + 32768 + (size_t)(lc16 + 16) * 1024 + ko);
                bf16x8 bh0 = *(const bf16x8*)(WFR + (ki * 2 + 0) * 1024 + l16);
                bf16x8 bh1 = *(const bf16x8*)(WFR + (ki * 2 + 1) * 1024 + l16);
                bf16x8 bl0 = *(const bf16x8*)(WFR + 32768 + (ki * 2 + 0) * 1024 + l16);
                bf16x8 bl1 = *(const bf16x8*)(WFR + 32768 + (ki * 2 + 1) * 1024 + l16);
                acc00 = __builtin_amdgcn_mfma_f32_16x16x32_bf16(ah0, bh0, acc00, 0, 0, 0);
                acc10 = __builtin_amdgcn_mfma_f32_16x16x32_bf16(ah1, bh0, acc10, 0, 0, 0);
                acc01 = __builtin_amdgcn_mfma_f32_16x16x32_bf16(ah0, bh1, acc01, 0, 0, 0);
                acc11 = __builtin_amdgcn_mfma_f32_16x16x32_bf16(ah1, bh1, acc11, 0, 0, 0);
                acc00 = __builtin_amdgcn_mfma_f32_16x16x32_bf16(al0, bh0, acc00, 0, 0, 0);
                acc10 = __builtin_amdgcn_mfma_f32_16x16x32_bf16(al1, bh0, acc10, 0, 0, 0);
                acc01 = __builtin_amdgcn_mfma_f32_16x16x32_bf16(al0, bh1, acc01, 0, 0, 0);
                acc11 = __builtin_amdgcn_mfma_f32_16x16x32_bf16(al1, bh1, acc11, 0, 0, 0);
                acc00 = __builtin_amdgcn_mfma_f32_16x16x32_bf16(ah0, bl0, acc00, 0, 0, 0);
                acc10 = __builtin_amdgcn_mfma_f32_16x16x32_bf16(ah1, bl0, acc10, 0, 0, 0);
                acc01 = __builtin_amdgcn_mfma_f32_16x16x32_bf16(ah0, bl1, acc01, 0, 0, 0);
                acc11 = __builtin_amdgcn_mfma_f32_16x16x32_bf16(ah1, bl1, acc11, 0, 0, 0);
            }
        }

        // ---- add xw (acc reg r <-> row lq4*4 + r (+16 rt), col lc16 (+16 ct)) ----
        acc00.x += bf2f((unsigned short)(u00.x & 0xffff));
        acc00.y += bf2f((unsigned short)(u00.x >> 16));
        acc00.z += bf2f((unsigned short)(u00.y & 0xffff));
        acc00.w += bf2f((unsigned short)(u00.y >> 16));
        acc10.x += bf2f((unsigned short)(u10.x & 0xffff));
        acc10.y += bf2f((unsigned short)(u10.x >> 16));
        acc10.z += bf2f((unsigned short)(u10.y & 0xffff));
        acc10.w += bf2f((unsigned short)(u10.y >> 16));
        acc01.x += bf2f((unsigned short)(u01.x & 0xffff));
        acc01.y += bf2f((unsigned short)(u01.x >> 16));
        acc01.z += bf2f((unsigned short)(u01.y & 0xffff));
        acc01.w += bf2f((unsigned short)(u01.y >> 16));
        acc11.x += bf2f((unsigned short)(u11.x & 0xffff));
        acc11.y += bf2f((unsigned short)(u11.x >> 16));
        acc11.z += bf2f((unsigned short)(u11.y & 0xffff));
        acc11.w += bf2f((unsigned short)(u11.y >> 16));

        // ---- z -> LDS (row = b, col = zc) ----
        {
            const int r0 = lq4 * 4;
            ZL[(r0 + 0) * 33 + lc16]      = acc00.x;
            ZL[(r0 + 1) * 33 + lc16]      = acc00.y;
            ZL[(r0 + 2) * 33 + lc16]      = acc00.z;
            ZL[(r0 + 3) * 33 + lc16]      = acc00.w;
            ZL[(r0 + 16) * 33 + lc16]     = acc10.x;
            ZL[(r0 + 17) * 33 + lc16]     = acc10.y;
            ZL[(r0 + 18) * 33 + lc16]     = acc10.z;
            ZL[(r0 + 19) * 33 + lc16]     = acc10.w;
            ZL[(r0 + 0) * 33 + lc16 + 16] = acc01.x;
            ZL[(r0 + 1) * 33 + lc16 + 16] = acc01.y;
            ZL[(r0 + 2) * 33 + lc16 + 16] = acc01.z;
            ZL[(r0 + 3) * 33 + lc16 + 16] = acc01.w;
            ZL[(r0 + 16) * 33 + lc16 + 16] = acc11.x;
            ZL[(r0 + 17) * 33 + lc16 + 16] = acc11.y;
            ZL[(r0 + 18) * 33 + lc16 + 16] = acc11.z;
            ZL[(r0 + 19) * 33 + lc16 + 16] = acc11.w;
        }

        // ---- gates: lane handles (b = lb, j = 2q + hi5), q = 0..3 ----
        char* hdst = hb + (s & 1) * 65536;
        #pragma unroll
        for (int q = 0; q < 4; ++q) {
            const int j = 2 * q + hi5;
            float zi = ZL[lb * 33 + j];
            float zf = ZL[lb * 33 + j + 8];
            float zg = ZL[lb * 33 + j + 16];
            float zo = ZL[lb * 33 + j + 24];
            float ig = sigf(zi);
            float fg = sigf(zf);
            float gg = tanhf_fast(zg);
            float og = sigf(zo);
            cq[q] = fmaf(fg, cq[q], ig * gg);
            float h = og * tanhf_fast(cq[q]);
            unsigned int hh = f2bf(h);
            unsigned int hl = f2bf(h - bf2f((unsigned short)hh));
            char* wp = hdst + (size_t)(lb * 512 + p * 8 + j) * 2;
            asm volatile("global_store_short %0, %1, off sc0 sc1"
                         :: "v"(wp), "v"(hh) : "memory");
            asm volatile("global_store_short %0, %1, off sc0 sc1"
                         :: "v"(wp + 32768), "v"(hl) : "memory");
            out[(size_t)lb * TSTEPS * OUTW + (size_t)t * OUTW + dir * HID + p * 8 + j] = h;
        }

        asm volatile("s_waitcnt vmcnt(0)" ::: "memory");
        if (l == 0) {
            __hip_atomic_fetch_add(&flg[s], 1, __ATOMIC_RELAXED, __HIP_MEMORY_SCOPE_AGENT);
        }
    }
}

extern "C" void kernel_launch(void* const* d_in, const int* in_sizes, int n_in,
                              void* d_out, int out_size, void* d_ws, size_t ws_size,
                              hipStream_t stream)
{
    const float* x     = (const float*)d_in[0];
    const float* Wi_f0 = (const float*)d_in[1];
    const float* Wh_f0 = (const float*)d_in[2];
    const float* b_f0  = (const float*)d_in[3];
    const float* Wi_b0 = (const float*)d_in[4];
    const float* Wh_b0 = (const float*)d_in[5];
    const float* b_b0  = (const float*)d_in[6];
    const float* Wi_f1 = (const float*)d_in[7];
    const float* Wh_f1 = (const float*)d_in[8];
    const float* b_f1  = (const float*)d_in[9];
    const float* Wi_b1 = (const float*)d_in[10];
    const float* Wh_b1 = (const float*)d_in[11];
    const float* b_b1  = (const float*)d_in[12];
    float* out = (float*)d_out;

    const size_t xw_elems = (size_t)MTOT * G4;                 // 33,554,432
    unsigned short* xwf = (unsigned short*)d_ws;
    unsigned short* xwb = xwf + xw_elems;
    char* tail = (char*)d_ws + 2 * xw_elems * sizeof(unsigned short);  // 128 MiB
    unsigned short* hbuf = (unsigned short*)tail;              // 256 KiB
    int* flags = (int*)(tail + 262144);                        // [layer][dir][512]

    (void)hipMemsetAsync(flags, 0, 2 * 2 * TSTEPS * sizeof(int), stream);

    dim3 ggrid(G4 / 128, MTOT / 128);
    dim3 gblock(256);
    dim3 sgrid(2 * NBLK_DIR);   // 128 blocks
    dim3 sblock(64);            // 1 wave
    const size_t smem = 65536 + 65536 + 32 * 33 * 4;           // 135,296 B

    gemm_xw<<<ggrid, gblock, 0, stream>>>(x, 256, Wi_f0, b_f0, xwf);
    gemm_xw<<<ggrid, gblock, 0, stream>>>(x, 256, Wi_b0, b_b0, xwb);
    lstm_scan4<<<sgrid, sblock, smem, stream>>>(xwf, xwb, Wh_f0, Wh_b0, out,
                                                hbuf, flags);
    gemm_xw<<<ggrid, gblock, 0, stream>>>(out, 1024, Wi_f1, b_f1, xwf);
    gemm_xw<<<ggrid, gblock, 0, stream>>>(out, 1024, Wi_b1, b_b1, xwb);
    lstm_scan4<<<sgrid, sblock, smem, stream>>>(xwf, xwb, Wh_f1, Wh_b1, out,
                                                hbuf, flags + 2 * TSTEPS);
}

// Round 6
// 8601.255 us; speedup vs baseline: 4.0761x; 1.1449x over previous
//
#include <hip/hip_runtime.h>
#include <stdint.h>

#define TSTEPS 512
#define BATCH  32
#define HID    512
#define G4     2048
#define OUTW   1024
#define MTOT   (TSTEPS * BATCH)   // 16384, m = t*32 + b

#define NBLK   16   // blocks per direction (4 waves each)
typedef __attribute__((ext_vector_type(8))) short bf16x8;
typedef __attribute__((ext_vector_type(4))) float f32x4;

__device__ __forceinline__ float sigf(float x) { return 1.0f / (1.0f + __expf(-x)); }
__device__ __forceinline__ float tanhf_fast(float x) { return 2.0f / (1.0f + __expf(-2.0f * x)) - 1.0f; }

__device__ __forceinline__ unsigned short f2bf(float f) {
    unsigned int u = __float_as_uint(f);
    u += 0x7fffu + ((u >> 16) & 1u);
    return (unsigned short)(u >> 16);
}
__device__ __forceinline__ float bf2f(unsigned short u) {
    return __uint_as_float((unsigned int)u << 16);
}

// ---------------------------------------------------------------------------
// Input-projection GEMM, TRANSPOSED output: XWt[n][m] (bf16), m = t*32 + b.
// ---------------------------------------------------------------------------
__global__ __launch_bounds__(256) void gemm_xw(
    const float* __restrict__ X, int K,
    const float* __restrict__ W,
    const float* __restrict__ bias,
    unsigned short* __restrict__ XWt)
{
    __shared__ float As[16][132];
    __shared__ float Bs[16][132];
    const int tid = threadIdx.x;
    const int n0 = blockIdx.x * 128;
    const int m0 = blockIdx.y * 128;
    const int tx = tid & 15;
    const int ty = tid >> 4;

    const int mA = tid >> 1;
    const int kA = (tid & 1) * 8;
    const int mg = m0 + mA;
    const float* arow = X + (size_t)(mg & 31) * ((size_t)TSTEPS * K) + (size_t)(mg >> 5) * K;

    const int kB = tid >> 4;
    const int nB = (tid & 15) * 8;
    const float* bptr = W + (size_t)kB * G4 + n0 + nB;

    float c[8][8];
    #pragma unroll
    for (int i = 0; i < 8; ++i)
        #pragma unroll
        for (int j = 0; j < 8; ++j) c[i][j] = 0.0f;

    for (int k0 = 0; k0 < K; k0 += 16) {
        float4 a0 = *(const float4*)(arow + k0 + kA);
        float4 a1 = *(const float4*)(arow + k0 + kA + 4);
        float4 b0 = *(const float4*)(bptr + (size_t)k0 * G4);
        float4 b1 = *(const float4*)(bptr + (size_t)k0 * G4 + 4);
        __syncthreads();
        As[kA + 0][mA] = a0.x; As[kA + 1][mA] = a0.y;
        As[kA + 2][mA] = a0.z; As[kA + 3][mA] = a0.w;
        As[kA + 4][mA] = a1.x; As[kA + 5][mA] = a1.y;
        As[kA + 6][mA] = a1.z; As[kA + 7][mA] = a1.w;
        *(float4*)&Bs[kB][nB]     = b0;
        *(float4*)&Bs[kB][nB + 4] = b1;
        __syncthreads();
        #pragma unroll
        for (int kk = 0; kk < 16; ++kk) {
            float4 av0 = *(const float4*)&As[kk][ty * 8];
            float4 av1 = *(const float4*)&As[kk][ty * 8 + 4];
            float4 bv0 = *(const float4*)&Bs[kk][tx * 8];
            float4 bv1 = *(const float4*)&Bs[kk][tx * 8 + 4];
            float a[8]  = {av0.x, av0.y, av0.z, av0.w, av1.x, av1.y, av1.z, av1.w};
            float bb[8] = {bv0.x, bv0.y, bv0.z, bv0.w, bv1.x, bv1.y, bv1.z, bv1.w};
            #pragma unroll
            for (int i = 0; i < 8; ++i)
                #pragma unroll
                for (int j = 0; j < 8; ++j)
                    c[i][j] = fmaf(a[i], bb[j], c[i][j]);
        }
    }

    float bn[8];
    #pragma unroll
    for (int j = 0; j < 8; ++j) bn[j] = bias[n0 + tx * 8 + j];

    #pragma unroll
    for (int j = 0; j < 8; ++j) {
        const int n = n0 + tx * 8 + j;
        unsigned int w0 = (unsigned)f2bf(c[0][j] + bn[j]) | ((unsigned)f2bf(c[1][j] + bn[j]) << 16);
        unsigned int w1 = (unsigned)f2bf(c[2][j] + bn[j]) | ((unsigned)f2bf(c[3][j] + bn[j]) << 16);
        unsigned int w2 = (unsigned)f2bf(c[4][j] + bn[j]) | ((unsigned)f2bf(c[5][j] + bn[j]) << 16);
        unsigned int w3 = (unsigned)f2bf(c[6][j] + bn[j]) | ((unsigned)f2bf(c[7][j] + bn[j]) << 16);
        uint4 pk; pk.x = w0; pk.y = w1; pk.z = w2; pk.w = w3;
        *(uint4*)(XWt + (size_t)n * MTOT + (m0 + ty * 8)) = pk;
    }
}

// ---------------------------------------------------------------------------
// MFMA recurrent scan, 4-wave blocks. 32 blocks x 256 thr. dir = blk&1, P = blk>>1.
// Wave w: p_eff = P*4+w owns h-cols [p_eff*8, +8) -> 32 zc; Wh frags in REGISTERS.
// h exchanged coalesced: [plane][P][b][j(32)] bf16, 8B dwordx2 stores, 16B chunk loads.
// LDS: h-stage 64KB + z 16.5KB. 1 block/CU; __launch_bounds__(256,1) -> 512 VGPR.
// ---------------------------------------------------------------------------
__global__ __launch_bounds__(256, 1) void lstm_scan5(
    const unsigned short* __restrict__ xw_f,  // [G4][MTOT] bf16
    const unsigned short* __restrict__ xw_b,
    const float* __restrict__ Wh_f,           // [512][2048] f32
    const float* __restrict__ Wh_b,
    float* __restrict__ out,                  // [B][T][1024] f32
    unsigned short* __restrict__ hbuf,        // [dir][parity][plane][P][b][32] bf16
    int* __restrict__ flags)                  // [dir][TSTEPS]
{
    extern __shared__ char smem[];
    char*  HST = smem;                        // plane*32768 + b*1024 + (kbyte ^ ((b&7)<<4))
    float* ZL  = (float*)(smem + 65536);      // [32 b][132] (128 zc + pad)

    const int tid  = threadIdx.x;
    const int l    = tid & 63;
    const int w    = tid >> 6;
    const int dir  = blockIdx.x & 1;
    const int P    = blockIdx.x >> 1;
    const int p_eff = P * 4 + w;
    const int lc16 = l & 15;
    const int lq4  = l >> 4;
    const int swz  = (lc16 & 7) << 4;

    const unsigned short* __restrict__ xw = dir ? xw_b : xw_f;
    const float* __restrict__ Wh = dir ? Wh_b : Wh_f;
    char* hb   = (char*)hbuf + (size_t)dir * 131072;
    int*  flg  = flags + dir * TSTEPS;

    // ---- one-time: Wh fragments -> registers (hi/lo bf16) ----
    bf16x8 wfh[16][2], wfl[16][2];
    #pragma unroll
    for (int ki = 0; ki < 16; ++ki) {
        #pragma unroll
        for (int ct = 0; ct < 2; ++ct) {
            const int zc  = ct * 16 + lc16;
            const int col = p_eff * 8 + (zc & 7) + 512 * (zc >> 3);
            const float* src = Wh + (size_t)(ki * 32 + lq4 * 8) * G4 + col;
            bf16x8 vh, vl;
            #pragma unroll
            for (int r = 0; r < 8; ++r) {
                float v = src[(size_t)r * G4];
                unsigned short h16 = f2bf(v);
                vh[r] = (short)h16;
                vl[r] = (short)f2bf(v - bf2f(h16));
            }
            wfh[ki][ct] = vh;
            wfl[ki][ct] = vl;
        }
    }

    // xw column bases (lane's two coltiles)
    const int gc0 = p_eff * 8 + (lc16 & 7) + 512 * (lc16 >> 3);
    const unsigned short* xc0 = xw + (size_t)gc0 * MTOT;
    const unsigned short* xc1 = xw + (size_t)(gc0 + 1024) * MTOT;

    // gate-thread mapping: b = tid&31, j-group jg = tid>>5 (cols jg*4..+3)
    const int gb = tid & 31;
    const int jg = tid >> 5;
    float* outg = out + (size_t)gb * TSTEPS * OUTW + dir * HID + P * 32 + jg * 4;
    float cq[4] = {0.f, 0.f, 0.f, 0.f};

    for (int s = 0; s < TSTEPS; ++s) {
        const int t = dir ? (TSTEPS - 1 - s) : s;

        const int xoff = t * 32 + lq4 * 4;
        uint2 u00 = *(const uint2*)(xc0 + xoff);
        uint2 u10 = *(const uint2*)(xc0 + xoff + 16);
        uint2 u01 = *(const uint2*)(xc1 + xoff);
        uint2 u11 = *(const uint2*)(xc1 + xoff + 16);

        f32x4 acc00 = {0,0,0,0}, acc01 = {0,0,0,0}, acc10 = {0,0,0,0}, acc11 = {0,0,0,0};

        if (s > 0) {
            if (tid == 0) {
                while (__hip_atomic_load(&flg[s - 1], __ATOMIC_RELAXED,
                                         __HIP_MEMORY_SCOPE_AGENT) < NBLK) { }
            }
            __syncthreads();

            // ---- stage h (64KB) from MALL into swizzled LDS, 2 batches of 8 ----
            const char* hsrc = hb + ((s - 1) & 1) * 65536;
            float4 rg[8];
            #pragma unroll
            for (int pass = 0; pass < 2; ++pass) {
                #pragma unroll
                for (int cc = 0; cc < 8; ++cc) {
                    const char* sp = hsrc + (pass * 8 + cc) * 4096 + tid * 16;
                    asm volatile("global_load_dwordx4 %0, %1, off sc0 sc1"
                                 : "=v"(rg[cc]) : "v"(sp) : "memory");
                }
                asm volatile("s_waitcnt vmcnt(0)" ::: "memory");
                __builtin_amdgcn_sched_barrier(0);
                #pragma unroll
                for (int cc = 0; cc < 8; ++cc) {
                    const int off = (pass * 8 + cc) * 4096 + tid * 16;
                    const int pl  = off >> 15;
                    const int ip  = off & 32767;
                    const int Pq  = ip >> 11;
                    const int b   = (ip >> 6) & 31;
                    const int jb  = ip & 63;
                    *(float4*)(HST + pl * 32768 + b * 1024 +
                               ((Pq * 64 + jb) ^ ((b & 7) << 4))) = rg[cc];
                }
            }
            __syncthreads();

            // ---- MFMA: B-frags from registers, A-frags from LDS ----
            #pragma unroll
            for (int ki = 0; ki < 16; ++ki) {
                const int ko = (ki * 64 + lq4 * 16) ^ swz;
                bf16x8 ah0 = *(const bf16x8*)(HST + (size_t)lc16 * 1024 + ko);
                bf16x8 ah1 = *(const bf16x8*)(HST + (size_t)(lc16 + 16) * 1024 + ko);
                bf16x8 al0 = *(const bf16x8*)(HST + 32768 + (size_t)lc16 * 1024 + ko);
                bf16x8 al1 = *(const bf16x8*)(HST + 32768 + (size_t)(lc16 + 16) * 1024 + ko);
                acc00 = __builtin_amdgcn_mfma_f32_16x16x32_bf16(ah0, wfh[ki][0], acc00, 0, 0, 0);
                acc10 = __builtin_amdgcn_mfma_f32_16x16x32_bf16(ah1, wfh[ki][0], acc10, 0, 0, 0);
                acc01 = __builtin_amdgcn_mfma_f32_16x16x32_bf16(ah0, wfh[ki][1], acc01, 0, 0, 0);
                acc11 = __builtin_amdgcn_mfma_f32_16x16x32_bf16(ah1, wfh[ki][1], acc11, 0, 0, 0);
                acc00 = __builtin_amdgcn_mfma_f32_16x16x32_bf16(al0, wfh[ki][0], acc00, 0, 0, 0);
                acc10 = __builtin_amdgcn_mfma_f32_16x16x32_bf16(al1, wfh[ki][0], acc10, 0, 0, 0);
                acc01 = __builtin_amdgcn_mfma_f32_16x16x32_bf16(al0, wfh[ki][1], acc01, 0, 0, 0);
                acc11 = __builtin_amdgcn_mfma_f32_16x16x32_bf16(al1, wfh[ki][1], acc11, 0, 0, 0);
                acc00 = __builtin_amdgcn_mfma_f32_16x16x32_bf16(ah0, wfl[ki][0], acc00, 0, 0, 0);
                acc10 = __builtin_amdgcn_mfma_f32_16x16x32_bf16(ah1, wfl[ki][0], acc10, 0, 0, 0);
                acc01 = __builtin_amdgcn_mfma_f32_16x16x32_bf16(ah0, wfl[ki][1], acc01, 0, 0, 0);
                acc11 = __builtin_amdgcn_mfma_f32_16x16x32_bf16(ah1, wfl[ki][1], acc11, 0, 0, 0);
            }
        }

        // ---- add xw ----
        acc00.x += bf2f((unsigned short)(u00.x & 0xffff));
        acc00.y += bf2f((unsigned short)(u00.x >> 16));
        acc00.z += bf2f((unsigned short)(u00.y & 0xffff));
        acc00.w += bf2f((unsigned short)(u00.y >> 16));
        acc10.x += bf2f((unsigned short)(u10.x & 0xffff));
        acc10.y += bf2f((unsigned short)(u10.x >> 16));
        acc10.z += bf2f((unsigned short)(u10.y & 0xffff));
        acc10.w += bf2f((unsigned short)(u10.y >> 16));
        acc01.x += bf2f((unsigned short)(u01.x & 0xffff));
        acc01.y += bf2f((unsigned short)(u01.x >> 16));
        acc01.z += bf2f((unsigned short)(u01.y & 0xffff));
        acc01.w += bf2f((unsigned short)(u01.y >> 16));
        acc11.x += bf2f((unsigned short)(u11.x & 0xffff));
        acc11.y += bf2f((unsigned short)(u11.x >> 16));
        acc11.z += bf2f((unsigned short)(u11.y & 0xffff));
        acc11.w += bf2f((unsigned short)(u11.y >> 16));

        // ---- z -> LDS: ZL[b][w*32 + zcl] ----
        {
            const int r0 = lq4 * 4;
            const int cb = w * 32 + lc16;
            ZL[(r0 + 0)  * 132 + cb]      = acc00.x;
            ZL[(r0 + 1)  * 132 + cb]      = acc00.y;
            ZL[(r0 + 2)  * 132 + cb]      = acc00.z;
            ZL[(r0 + 3)  * 132 + cb]      = acc00.w;
            ZL[(r0 + 16) * 132 + cb]      = acc10.x;
            ZL[(r0 + 17) * 132 + cb]      = acc10.y;
            ZL[(r0 + 18) * 132 + cb]      = acc10.z;
            ZL[(r0 + 19) * 132 + cb]      = acc10.w;
            ZL[(r0 + 0)  * 132 + cb + 16] = acc01.x;
            ZL[(r0 + 1)  * 132 + cb + 16] = acc01.y;
            ZL[(r0 + 2)  * 132 + cb + 16] = acc01.z;
            ZL[(r0 + 3)  * 132 + cb + 16] = acc01.w;
            ZL[(r0 + 16) * 132 + cb + 16] = acc11.x;
            ZL[(r0 + 17) * 132 + cb + 16] = acc11.y;
            ZL[(r0 + 18) * 132 + cb + 16] = acc11.z;
            ZL[(r0 + 19) * 132 + cb + 16] = acc11.w;
        }
        __syncthreads();

        // ---- gates: thread (b=gb, cols jg*4..+3); coalesced h publish ----
        {
            const float* zr = &ZL[gb * 132];
            float hv[4];
            #pragma unroll
            for (int q = 0; q < 4; ++q) {
                const int j  = jg * 4 + q;         // block-local h-col 0..31
                const int wv = j >> 3;             // producing wave
                const int jj = j & 7;
                float zi = zr[wv * 32 + jj];
                float zf = zr[wv * 32 + 8 + jj];
                float zg = zr[wv * 32 + 16 + jj];
                float zo = zr[wv * 32 + 24 + jj];
                float ig = sigf(zi);
                float fg = sigf(zf);
                float gg = tanhf_fast(zg);
                float og = sigf(zo);
                cq[q] = fmaf(fg, cq[q], ig * gg);
                hv[q] = og * tanhf_fast(cq[q]);
            }
            unsigned short h0 = f2bf(hv[0]), h1 = f2bf(hv[1]);
            unsigned short h2 = f2bf(hv[2]), h3 = f2bf(hv[3]);
            uint2 hi_pk, lo_pk;
            hi_pk.x = (unsigned)h0 | ((unsigned)h1 << 16);
            hi_pk.y = (unsigned)h2 | ((unsigned)h3 << 16);
            lo_pk.x = (unsigned)f2bf(hv[0] - bf2f(h0)) | ((unsigned)f2bf(hv[1] - bf2f(h1)) << 16);
            lo_pk.y = (unsigned)f2bf(hv[2] - bf2f(h2)) | ((unsigned)f2bf(hv[3] - bf2f(h3)) << 16);
            char* wp = hb + (s & 1) * 65536 + P * 2048 + gb * 64 + jg * 8;
            asm volatile("global_store_dwordx2 %0, %1, off sc0 sc1"
                         :: "v"(wp), "v"(hi_pk) : "memory");
            asm volatile("global_store_dwordx2 %0, %1, off sc0 sc1"
                         :: "v"(wp + 32768), "v"(lo_pk) : "memory");
            float4 ov; ov.x = hv[0]; ov.y = hv[1]; ov.z = hv[2]; ov.w = hv[3];
            *(float4*)&outg[(size_t)t * OUTW] = ov;
        }

        asm volatile("s_waitcnt vmcnt(0)" ::: "memory");
        __syncthreads();
        if (tid == 0) {
            __hip_atomic_fetch_add(&flg[s], 1, __ATOMIC_RELAXED, __HIP_MEMORY_SCOPE_AGENT);
        }
    }
}

extern "C" void kernel_launch(void* const* d_in, const int* in_sizes, int n_in,
                              void* d_out, int out_size, void* d_ws, size_t ws_size,
                              hipStream_t stream)
{
    const float* x     = (const float*)d_in[0];
    const float* Wi_f0 = (const float*)d_in[1];
    const float* Wh_f0 = (const float*)d_in[2];
    const float* b_f0  = (const float*)d_in[3];
    const float* Wi_b0 = (const float*)d_in[4];
    const float* Wh_b0 = (const float*)d_in[5];
    const float* b_b0  = (const float*)d_in[6];
    const float* Wi_f1 = (const float*)d_in[7];
    const float* Wh_f1 = (const float*)d_in[8];
    const float* b_f1  = (const float*)d_in[9];
    const float* Wi_b1 = (const float*)d_in[10];
    const float* Wh_b1 = (const float*)d_in[11];
    const float* b_b1  = (const float*)d_in[12];
    float* out = (float*)d_out;

    const size_t xw_elems = (size_t)MTOT * G4;                 // 33,554,432
    unsigned short* xwf = (unsigned short*)d_ws;
    unsigned short* xwb = xwf + xw_elems;
    char* tail = (char*)d_ws + 2 * xw_elems * sizeof(unsigned short);  // 128 MiB
    unsigned short* hbuf = (unsigned short*)tail;              // 256 KiB
    int* flags = (int*)(tail + 262144);                        // [layer][dir][512]

    (void)hipMemsetAsync(flags, 0, 2 * 2 * TSTEPS * sizeof(int), stream);

    dim3 ggrid(G4 / 128, MTOT / 128);
    dim3 gblock(256);
    dim3 sgrid(2 * NBLK);       // 32 blocks
    dim3 sblock(256);           // 4 waves
    const size_t smem = 65536 + 32 * 132 * 4;                  // 82,432 B

    gemm_xw<<<ggrid, gblock, 0, stream>>>(x, 256, Wi_f0, b_f0, xwf);
    gemm_xw<<<ggrid, gblock, 0, stream>>>(x, 256, Wi_b0, b_b0, xwb);
    lstm_scan5<<<sgrid, sblock, smem, stream>>>(xwf, xwb, Wh_f0, Wh_b0, out,
                                                hbuf, flags);
    gemm_xw<<<ggrid, gblock, 0, stream>>>(out, 1024, Wi_f1, b_f1, xwf);
    gemm_xw<<<ggrid, gblock, 0, stream>>>(out, 1024, Wi_b1, b_b1, xwb);
    lstm_scan5<<<sgrid, sblock, smem, stream>>>(xwf, xwb, Wh_f1, Wh_b1, out,
                                                hbuf, flags + 2 * TSTEPS);
}

// Round 7
// 6149.514 us; speedup vs baseline: 5.7011x; 1.3987x over previous
//
#include <hip/hip_runtime.h>
#include <stdint.h>

#define TSTEPS 512
#define BATCH  32
#define HID    512
#define G4     2048
#define OUTW   1024
#define MTOT   (TSTEPS * BATCH)   // 16384, m = t*32 + b

#define NBLK   16                  // scan blocks per direction
#define HROW   1040                // padded LDS row stride (bytes) for h-stage
#define HPLANE (32 * HROW)         // 33280 B per plane

typedef __attribute__((ext_vector_type(8))) short bf16x8;
typedef __attribute__((ext_vector_type(4))) float f32x4;

__device__ __forceinline__ float sigf(float x) { return 1.0f / (1.0f + __expf(-x)); }
__device__ __forceinline__ float tanhf_fast(float x) { return 2.0f / (1.0f + __expf(-2.0f * x)) - 1.0f; }

__device__ __forceinline__ unsigned short f2bf(float f) {
    unsigned int u = __float_as_uint(f);
    u += 0x7fffu + ((u >> 16) & 1u);
    return (unsigned short)(u >> 16);
}
__device__ __forceinline__ float bf2f(unsigned short u) {
    return __uint_as_float((unsigned int)u << 16);
}

// ---------------------------------------------------------------------------
// MFMA input-projection GEMM, transposed bf16 output XWt[n][m], m = t*32+b.
// 128x128 tile, BK=32 real k, hi/lo split of A and B staged through LDS,
// 3-product accumulation (AhBh + AlBh + AhBl) ~ fp32 accuracy.
// LDS: A[128][144B] + B[128][144B] = 36864 B (rows hold [hi 64B | lo 64B]).
// ---------------------------------------------------------------------------
__global__ __launch_bounds__(256) void gemm_xw_mfma(
    const float* __restrict__ X, int K,
    const float* __restrict__ W,
    const float* __restrict__ bias,
    unsigned short* __restrict__ XWt)
{
    extern __shared__ char gsm[];
    char* Abuf = gsm;            // row r: r*144 + plane*64 + k*2
    char* Bbuf = gsm + 18432;    // col c: c*144 + plane*64 + k*2

    const int tid = threadIdx.x;
    const int n0 = blockIdx.x * 128;
    const int m0 = blockIdx.y * 128;
    const int w  = tid >> 6;
    const int l  = tid & 63;
    const int lc16 = l & 15;
    const int lq4  = l >> 4;
    const int wr = w >> 1, wc = w & 1;

    // A staging ids: row ar (0..127), k-half akh
    const int ar  = tid >> 1;
    const int akh = tid & 1;
    const int mg  = m0 + ar;
    const float* aptr = X + (size_t)(mg & 31) * ((size_t)TSTEPS * K)
                          + (size_t)(mg >> 5) * K + akh * 16;
    // B staging ids: n-pair bnp (0..63), k-group bkg (0..3)
    const int bnp = tid & 63;
    const int bkg = tid >> 6;
    const float* bptr = W + n0 + bnp * 2;

    f32x4 acc[4][4];
    #pragma unroll
    for (int i = 0; i < 4; ++i)
        #pragma unroll
        for (int j = 0; j < 4; ++j) acc[i][j] = (f32x4){0.f, 0.f, 0.f, 0.f};

    const int KT = K >> 5;
    float4 a0, a1, a2, a3;
    float2 bw[8];

#define GLOADS(KT0) do { \
    const float* ap = aptr + (KT0) * 32; \
    a0 = *(const float4*)(ap);      a1 = *(const float4*)(ap + 4); \
    a2 = *(const float4*)(ap + 8);  a3 = *(const float4*)(ap + 12); \
    _Pragma("unroll") \
    for (int i = 0; i < 8; ++i) \
        bw[i] = *(const float2*)(bptr + (size_t)((KT0) * 32 + bkg * 8 + i) * G4); \
} while (0)

    GLOADS(0);

    for (int kt = 0; kt < KT; ++kt) {
        __syncthreads();
        // ---- convert + stage A ----
        {
            float av[16] = {a0.x,a0.y,a0.z,a0.w, a1.x,a1.y,a1.z,a1.w,
                            a2.x,a2.y,a2.z,a2.w, a3.x,a3.y,a3.z,a3.w};
            bf16x8 h0, h1, l0, l1;
            #pragma unroll
            for (int i = 0; i < 8; ++i) {
                unsigned short hh = f2bf(av[i]);
                h0[i] = (short)hh; l0[i] = (short)f2bf(av[i] - bf2f(hh));
                unsigned short hh2 = f2bf(av[i + 8]);
                h1[i] = (short)hh2; l1[i] = (short)f2bf(av[i + 8] - bf2f(hh2));
            }
            char* ab = Abuf + ar * 144 + akh * 32;
            *(bf16x8*)(ab)           = h0;
            *(bf16x8*)(ab + 16)      = h1;
            *(bf16x8*)(ab + 64)      = l0;
            *(bf16x8*)(ab + 80)      = l1;
        }
        // ---- convert + stage B (transpose 2 cols) ----
        {
            bf16x8 bh[2], bl[2];
            #pragma unroll
            for (int c = 0; c < 2; ++c) {
                #pragma unroll
                for (int i = 0; i < 8; ++i) {
                    float v = c ? bw[i].y : bw[i].x;
                    unsigned short hh = f2bf(v);
                    bh[c][i] = (short)hh;
                    bl[c][i] = (short)f2bf(v - bf2f(hh));
                }
                char* bb = Bbuf + (bnp * 2 + c) * 144 + bkg * 16;
                *(bf16x8*)(bb)      = bh[c];
                *(bf16x8*)(bb + 64) = bl[c];
            }
        }
        __syncthreads();
        if (kt + 1 < KT) GLOADS(kt + 1);   // prefetch overlaps MFMA

        // ---- MFMA: 3 products x 16 frags ----
        bf16x8 ah[4], al[4], bh[4], bl[4];
        #pragma unroll
        for (int rt = 0; rt < 4; ++rt) {
            const char* ab = Abuf + (wr * 64 + rt * 16 + lc16) * 144 + lq4 * 16;
            ah[rt] = *(const bf16x8*)(ab);
            al[rt] = *(const bf16x8*)(ab + 64);
        }
        #pragma unroll
        for (int ct = 0; ct < 4; ++ct) {
            const char* bb = Bbuf + (wc * 64 + ct * 16 + lc16) * 144 + lq4 * 16;
            bh[ct] = *(const bf16x8*)(bb);
            bl[ct] = *(const bf16x8*)(bb + 64);
        }
        #pragma unroll
        for (int rt = 0; rt < 4; ++rt)
            #pragma unroll
            for (int ct = 0; ct < 4; ++ct) {
                acc[rt][ct] = __builtin_amdgcn_mfma_f32_16x16x32_bf16(ah[rt], bh[ct], acc[rt][ct], 0, 0, 0);
                acc[rt][ct] = __builtin_amdgcn_mfma_f32_16x16x32_bf16(al[rt], bh[ct], acc[rt][ct], 0, 0, 0);
                acc[rt][ct] = __builtin_amdgcn_mfma_f32_16x16x32_bf16(ah[rt], bl[ct], acc[rt][ct], 0, 0, 0);
            }
    }
#undef GLOADS

    // ---- epilogue: +bias, bf16, transposed store (4 consecutive m per lane) ----
    #pragma unroll
    for (int ct = 0; ct < 4; ++ct) {
        const int n = n0 + wc * 64 + ct * 16 + lc16;
        const float bn = bias[n];
        #pragma unroll
        for (int rt = 0; rt < 4; ++rt) {
            const int m = m0 + wr * 64 + rt * 16 + lq4 * 4;
            f32x4 v = acc[rt][ct];
            uint2 pk;
            pk.x = (unsigned)f2bf(v.x + bn) | ((unsigned)f2bf(v.y + bn) << 16);
            pk.y = (unsigned)f2bf(v.z + bn) | ((unsigned)f2bf(v.w + bn) << 16);
            *(uint2*)(XWt + (size_t)n * MTOT + m) = pk;
        }
    }
}

// ---------------------------------------------------------------------------
// MFMA recurrent scan. 32 blocks x 256 thr (4 waves). dir = blk&1, P = blk>>1.
// Wave w: p_eff = P*4+w owns h-cols [p_eff*8,+8) -> 32 zc; Wh frags in regs.
// Per-producer store-flags (no atomics); single-RT staging; padded LDS rows.
// ---------------------------------------------------------------------------
__global__ __launch_bounds__(256, 1) void lstm_scan6(
    const unsigned short* __restrict__ xw_f,  // [G4][MTOT] bf16
    const unsigned short* __restrict__ xw_b,
    const float* __restrict__ Wh_f,           // [512][2048] f32
    const float* __restrict__ Wh_b,
    float* __restrict__ out,                  // [B][T][1024] f32
    unsigned short* __restrict__ hbuf,        // [dir][parity][plane][P][b][32] bf16
    int* __restrict__ flags,                  // [dir][TSTEPS][16]
    int lval)                                 // layer+1
{
    extern __shared__ char smem[];
    char*  HST = smem;                        // pl*HPLANE + b*HROW + hcol*2
    float* ZL  = (float*)(smem + 2 * HPLANE); // [32 b][132]

    const int tid  = threadIdx.x;
    const int l    = tid & 63;
    const int w    = tid >> 6;
    const int dir  = blockIdx.x & 1;
    const int P    = blockIdx.x >> 1;
    const int p_eff = P * 4 + w;
    const int lc16 = l & 15;
    const int lq4  = l >> 4;

    const unsigned short* __restrict__ xw = dir ? xw_b : xw_f;
    const float* __restrict__ Wh = dir ? Wh_b : Wh_f;
    char* hb  = (char*)hbuf + (size_t)dir * 131072;
    int*  flg = flags + dir * TSTEPS * 16;

    // ---- one-time: Wh fragments -> registers (hi/lo bf16) ----
    bf16x8 wfh[16][2], wfl[16][2];
    #pragma unroll
    for (int ki = 0; ki < 16; ++ki) {
        #pragma unroll
        for (int ct = 0; ct < 2; ++ct) {
            const int zc  = ct * 16 + lc16;
            const int col = p_eff * 8 + (zc & 7) + 512 * (zc >> 3);
            const float* src = Wh + (size_t)(ki * 32 + lq4 * 8) * G4 + col;
            bf16x8 vh, vl;
            #pragma unroll
            for (int r = 0; r < 8; ++r) {
                float v = src[(size_t)r * G4];
                unsigned short h16 = f2bf(v);
                vh[r] = (short)h16;
                vl[r] = (short)f2bf(v - bf2f(h16));
            }
            wfh[ki][ct] = vh;
            wfl[ki][ct] = vl;
        }
    }

    const int gc0 = p_eff * 8 + (lc16 & 7) + 512 * (lc16 >> 3);
    const unsigned short* xc0 = xw + (size_t)gc0 * MTOT;
    const unsigned short* xc1 = xw + (size_t)(gc0 + 1024) * MTOT;

    const int gb = tid & 31;
    const int jg = tid >> 5;
    float* outg = out + (size_t)gb * TSTEPS * OUTW + dir * HID + P * 32 + jg * 4;
    float cq[4] = {0.f, 0.f, 0.f, 0.f};

    for (int s = 0; s < TSTEPS; ++s) {
        const int t = dir ? (TSTEPS - 1 - s) : s;

        const int xoff = t * 32 + lq4 * 4;
        uint2 u00 = *(const uint2*)(xc0 + xoff);
        uint2 u10 = *(const uint2*)(xc0 + xoff + 16);
        uint2 u01 = *(const uint2*)(xc1 + xoff);
        uint2 u11 = *(const uint2*)(xc1 + xoff + 16);

        f32x4 acc00 = {0,0,0,0}, acc01 = {0,0,0,0}, acc10 = {0,0,0,0}, acc11 = {0,0,0,0};

        if (s > 0) {
            // ---- all-lane poll of the 16 per-producer flag slots ----
            {
                const int* fp = &flg[(s - 1) * 16 + (l & 15)];
                int fv;
                do {
                    asm volatile("global_load_dword %0, %1, off sc0 sc1\n\t"
                                 "s_waitcnt vmcnt(0)"
                                 : "=v"(fv) : "v"(fp) : "memory");
                } while (__any(fv != lval));
            }
            // ---- issue all 16 staging loads, then barrier (flight overlaps) ----
            const char* hsrc = hb + ((s - 1) & 1) * 65536;
            float4 rg[16];
            #pragma unroll
            for (int c = 0; c < 16; ++c) {
                const char* sp = hsrc + c * 4096 + tid * 16;
                asm volatile("global_load_dwordx4 %0, %1, off sc0 sc1"
                             : "=v"(rg[c]) : "v"(sp) : "memory");
            }
            __syncthreads();   // prev step's LDS reads complete before overwrite

#define STG_WRITE(C0) do { \
            _Pragma("unroll") \
            for (int c = (C0); c < (C0) + 8; ++c) { \
                const int off = c * 4096 + tid * 16; \
                const int pl  = off >> 15; \
                const int ip  = off & 32767; \
                const int Pq  = ip >> 11; \
                const int b   = (ip >> 6) & 31; \
                const int jb  = ip & 63; \
                *(float4*)(HST + pl * HPLANE + b * HROW + Pq * 64 + jb) = rg[c]; \
            } } while (0)
            asm volatile("s_waitcnt vmcnt(8)" ::: "memory");
            __builtin_amdgcn_sched_barrier(0);
            STG_WRITE(0);
            asm volatile("s_waitcnt vmcnt(0)" ::: "memory");
            __builtin_amdgcn_sched_barrier(0);
            STG_WRITE(8);
#undef STG_WRITE
            __syncthreads();

            // ---- MFMA: A-frags from padded LDS, B-frags from registers ----
            #pragma unroll
            for (int ki = 0; ki < 16; ++ki) {
                const int ko = ki * 64 + lq4 * 16;
                bf16x8 ah0 = *(const bf16x8*)(HST + (size_t)lc16 * HROW + ko);
                bf16x8 ah1 = *(const bf16x8*)(HST + (size_t)(lc16 + 16) * HROW + ko);
                bf16x8 al0 = *(const bf16x8*)(HST + HPLANE + (size_t)lc16 * HROW + ko);
                bf16x8 al1 = *(const bf16x8*)(HST + HPLANE + (size_t)(lc16 + 16) * HROW + ko);
                acc00 = __builtin_amdgcn_mfma_f32_16x16x32_bf16(ah0, wfh[ki][0], acc00, 0, 0, 0);
                acc10 = __builtin_amdgcn_mfma_f32_16x16x32_bf16(ah1, wfh[ki][0], acc10, 0, 0, 0);
                acc01 = __builtin_amdgcn_mfma_f32_16x16x32_bf16(ah0, wfh[ki][1], acc01, 0, 0, 0);
                acc11 = __builtin_amdgcn_mfma_f32_16x16x32_bf16(ah1, wfh[ki][1], acc11, 0, 0, 0);
                acc00 = __builtin_amdgcn_mfma_f32_16x16x32_bf16(al0, wfh[ki][0], acc00, 0, 0, 0);
                acc10 = __builtin_amdgcn_mfma_f32_16x16x32_bf16(al1, wfh[ki][0], acc10, 0, 0, 0);
                acc01 = __builtin_amdgcn_mfma_f32_16x16x32_bf16(al0, wfh[ki][1], acc01, 0, 0, 0);
                acc11 = __builtin_amdgcn_mfma_f32_16x16x32_bf16(al1, wfh[ki][1], acc11, 0, 0, 0);
                acc00 = __builtin_amdgcn_mfma_f32_16x16x32_bf16(ah0, wfl[ki][0], acc00, 0, 0, 0);
                acc10 = __builtin_amdgcn_mfma_f32_16x16x32_bf16(ah1, wfl[ki][0], acc10, 0, 0, 0);
                acc01 = __builtin_amdgcn_mfma_f32_16x16x32_bf16(ah0, wfl[ki][1], acc01, 0, 0, 0);
                acc11 = __builtin_amdgcn_mfma_f32_16x16x32_bf16(ah1, wfl[ki][1], acc11, 0, 0, 0);
            }
        }

        // ---- add xw ----
        acc00.x += bf2f((unsigned short)(u00.x & 0xffff));
        acc00.y += bf2f((unsigned short)(u00.x >> 16));
        acc00.z += bf2f((unsigned short)(u00.y & 0xffff));
        acc00.w += bf2f((unsigned short)(u00.y >> 16));
        acc10.x += bf2f((unsigned short)(u10.x & 0xffff));
        acc10.y += bf2f((unsigned short)(u10.x >> 16));
        acc10.z += bf2f((unsigned short)(u10.y & 0xffff));
        acc10.w += bf2f((unsigned short)(u10.y >> 16));
        acc01.x += bf2f((unsigned short)(u01.x & 0xffff));
        acc01.y += bf2f((unsigned short)(u01.x >> 16));
        acc01.z += bf2f((unsigned short)(u01.y & 0xffff));
        acc01.w += bf2f((unsigned short)(u01.y >> 16));
        acc11.x += bf2f((unsigned short)(u11.x & 0xffff));
        acc11.y += bf2f((unsigned short)(u11.x >> 16));
        acc11.z += bf2f((unsigned short)(u11.y & 0xffff));
        acc11.w += bf2f((unsigned short)(u11.y >> 16));

        // ---- z -> LDS: ZL[b][w*32 + zcl] ----
        {
            const int r0 = lq4 * 4;
            const int cb = w * 32 + lc16;
            ZL[(r0 + 0)  * 132 + cb]      = acc00.x;
            ZL[(r0 + 1)  * 132 + cb]      = acc00.y;
            ZL[(r0 + 2)  * 132 + cb]      = acc00.z;
            ZL[(r0 + 3)  * 132 + cb]      = acc00.w;
            ZL[(r0 + 16) * 132 + cb]      = acc10.x;
            ZL[(r0 + 17) * 132 + cb]      = acc10.y;
            ZL[(r0 + 18) * 132 + cb]      = acc10.z;
            ZL[(r0 + 19) * 132 + cb]      = acc10.w;
            ZL[(r0 + 0)  * 132 + cb + 16] = acc01.x;
            ZL[(r0 + 1)  * 132 + cb + 16] = acc01.y;
            ZL[(r0 + 2)  * 132 + cb + 16] = acc01.z;
            ZL[(r0 + 3)  * 132 + cb + 16] = acc01.w;
            ZL[(r0 + 16) * 132 + cb + 16] = acc11.x;
            ZL[(r0 + 17) * 132 + cb + 16] = acc11.y;
            ZL[(r0 + 18) * 132 + cb + 16] = acc11.z;
            ZL[(r0 + 19) * 132 + cb + 16] = acc11.w;
        }
        __syncthreads();

        // ---- gates; coalesced h publish ----
        float hv[4];
        {
            const float* zr = &ZL[gb * 132];
            #pragma unroll
            for (int q = 0; q < 4; ++q) {
                const int j  = jg * 4 + q;
                const int wv = j >> 3;
                const int jj = j & 7;
                float zi = zr[wv * 32 + jj];
                float zf = zr[wv * 32 + 8 + jj];
                float zg = zr[wv * 32 + 16 + jj];
                float zo = zr[wv * 32 + 24 + jj];
                float ig = sigf(zi);
                float fg = sigf(zf);
                float gg = tanhf_fast(zg);
                float og = sigf(zo);
                cq[q] = fmaf(fg, cq[q], ig * gg);
                hv[q] = og * tanhf_fast(cq[q]);
            }
            unsigned short h0 = f2bf(hv[0]), h1 = f2bf(hv[1]);
            unsigned short h2 = f2bf(hv[2]), h3 = f2bf(hv[3]);
            uint2 hi_pk, lo_pk;
            hi_pk.x = (unsigned)h0 | ((unsigned)h1 << 16);
            hi_pk.y = (unsigned)h2 | ((unsigned)h3 << 16);
            lo_pk.x = (unsigned)f2bf(hv[0] - bf2f(h0)) | ((unsigned)f2bf(hv[1] - bf2f(h1)) << 16);
            lo_pk.y = (unsigned)f2bf(hv[2] - bf2f(h2)) | ((unsigned)f2bf(hv[3] - bf2f(h3)) << 16);
            char* wp = hb + (s & 1) * 65536 + P * 2048 + gb * 64 + jg * 8;
            asm volatile("global_store_dwordx2 %0, %1, off sc0 sc1"
                         :: "v"(wp), "v"(hi_pk) : "memory");
            asm volatile("global_store_dwordx2 %0, %1, off sc0 sc1"
                         :: "v"(wp + 32768), "v"(lo_pk) : "memory");
        }
        asm volatile("s_waitcnt vmcnt(0)" ::: "memory");  // h stores at MALL
        __syncthreads();                                  // ...for ALL waves
        if (tid == 0) {
            int* fp = &flg[s * 16 + P];
            asm volatile("global_store_dword %0, %1, off sc0 sc1"
                         :: "v"(fp), "v"(lval) : "memory");
        }
        // output store off the critical path
        float4 ov; ov.x = hv[0]; ov.y = hv[1]; ov.z = hv[2]; ov.w = hv[3];
        *(float4*)&outg[(size_t)t * OUTW] = ov;
    }
}

extern "C" void kernel_launch(void* const* d_in, const int* in_sizes, int n_in,
                              void* d_out, int out_size, void* d_ws, size_t ws_size,
                              hipStream_t stream)
{
    const float* x     = (const float*)d_in[0];
    const float* Wi_f0 = (const float*)d_in[1];
    const float* Wh_f0 = (const float*)d_in[2];
    const float* b_f0  = (const float*)d_in[3];
    const float* Wi_b0 = (const float*)d_in[4];
    const float* Wh_b0 = (const float*)d_in[5];
    const float* b_b0  = (const float*)d_in[6];
    const float* Wi_f1 = (const float*)d_in[7];
    const float* Wh_f1 = (const float*)d_in[8];
    const float* b_f1  = (const float*)d_in[9];
    const float* Wi_b1 = (const float*)d_in[10];
    const float* Wh_b1 = (const float*)d_in[11];
    const float* b_b1  = (const float*)d_in[12];
    float* out = (float*)d_out;

    const size_t xw_elems = (size_t)MTOT * G4;                 // 33,554,432
    unsigned short* xwf = (unsigned short*)d_ws;
    unsigned short* xwb = xwf + xw_elems;
    char* tail = (char*)d_ws + 2 * xw_elems * sizeof(unsigned short);  // 128 MiB
    unsigned short* hbuf = (unsigned short*)tail;              // 256 KiB
    int* flags = (int*)(tail + 262144);                        // [dir][512][16] = 64 KiB

    (void)hipMemsetAsync(flags, 0, 2 * TSTEPS * 16 * sizeof(int), stream);

    dim3 ggrid(G4 / 128, MTOT / 128);                          // (16, 128)
    dim3 gblock(256);
    const size_t gsmem = 36864;
    dim3 sgrid(2 * NBLK);                                      // 32 blocks
    dim3 sblock(256);
    const size_t ssmem = 2 * HPLANE + 32 * 132 * 4;            // 83,456 B

    gemm_xw_mfma<<<ggrid, gblock, gsmem, stream>>>(x, 256, Wi_f0, b_f0, xwf);
    gemm_xw_mfma<<<ggrid, gblock, gsmem, stream>>>(x, 256, Wi_b0, b_b0, xwb);
    lstm_scan6<<<sgrid, sblock, ssmem, stream>>>(xwf, xwb, Wh_f0, Wh_b0, out,
                                                 hbuf, flags, 1);
    gemm_xw_mfma<<<ggrid, gblock, gsmem, stream>>>(out, 1024, Wi_f1, b_f1, xwf);
    gemm_xw_mfma<<<ggrid, gblock, gsmem, stream>>>(out, 1024, Wi_b1, b_b1, xwb);
    lstm_scan6<<<sgrid, sblock, ssmem, stream>>>(xwf, xwb, Wh_f1, Wh_b1, out,
                                                 hbuf, flags, 2);
}